// Round 2
// baseline (1669.524 us; speedup 1.0000x reference)
//
#include <hip/hip_runtime.h>

// NLReader bidirectional LSTM, MI355X — persistent scan, XCD-local L2 relay.
//
// Round-11: the relay chain leaves MALL and moves into ONE XCD's L2.
//  * 1024 blocks launched; each reads HW_REG_XCC_ID and claims a slot in a
//    per-XCD counter. Teams of 32 blocks (16 hidden units each) form per
//    (xcd, slot/32); the first two completed teams elect dir 0 / dir 1 (the
//    32nd claimer registers via atomic). All other blocks exit. Team members
//    are co-resident on one XCD by construction (they claimed while running
//    there; blocks never migrate). Pigeonhole over >=512 resident claims
//    guarantees >=2 teams complete -> no deadlock.
//  * h relay: 8-deep ROTATING per-step buffers (fresh addresses; 4 KB pad
//    between slots) written with sc0 (L2) stores, acked with vmcnt(0), read
//    with one asm node of 16 global_load_dwordx4 sc0. Fresh addresses make
//    consumer reads compulsory L1 misses even if sc0's L1-bypass is a no-op.
//  * flags: dual-posted. Primary sc0 (same-XCD L2, ~200cyc detect); mirror
//    sc1 (MALL). Consumer spins on sc0, checks the sc1 mirror every 8 iters:
//    if sc0 polling were stale it only DELAYS (flags monotone) and the MALL
//    mirror rescues progress — no deadlock mode. h data is safe under both
//    paths because producer/consumer share the XCD's L2.
//  * 16 units/block (32 blocks/dir): halves per-step h read traffic (2 MB/
//    step/dir from L2) and halves the producer set the __all barrier spans.
//  * xproj prepass re-tiled: 1024 blocks (dir x kb(32) x 16 step-groups),
//    4 blocks/CU — removes the ~350us serialized prepass of round 10.
//  * ws overlay: ebf (8 MB, dead after xproj) shares space with the scan's
//    flag+hrot region (1.1 MB), zeroed between xproj and lstm_scan.
//    WS_NEED = 142,606,336 B <= round-10's granted 142,872,576 B.
//
// Block (dir, kb in [0,32)) owns 16 hidden units as 64 permuted gate cols:
//   tile t in [0,4), lane col c in [0,16): gate g = c&3, unit jj = 4*(c>>2)+t
//   orig Wih/Whh row = g*512 + kb*16 + jj.

typedef float  f32x4  __attribute__((ext_vector_type(4)));
typedef __bf16 bf16x8 __attribute__((ext_vector_type(8)));
typedef __bf16 bf16;

// ---- new-path ws layout ----
#define FLAG2_OFF ((size_t)0)          // 256 u32 sc0 flags (L2 domain)
#define FLAGM_OFF ((size_t)4096)       // 256 u32 sc1 mirror flags (MALL)
#define CLAIM_OFF ((size_t)8192)       // cnt[8], dirclaim, teamdir[2]
#define HR_OFF    ((size_t)16384)      // rotating h: 2 dirs x 8 slots
#define HR_STEP   ((size_t)69632)      // 64x512 bf16 (65536) + 4KB pad
#define HR_DIR    ((size_t)(8 * 69632))
#define SCAN_ZERO (HR_OFF + 2 * HR_DIR)          // 1,130,496 B
#define EBF_OFF   ((size_t)0)                    // overlays scan region
#define EBF_BYTES ((size_t)8388608)              // 8192 rows x 512 bf16
#define XP_OFF    ((size_t)8388608)
#define XP_BYTES  ((size_t)134217728)            // 2*32*128*4096 f32
#define WS_NEED   (XP_OFF + XP_BYTES)            // 142,606,336 B

// ---- legacy (round-9) ws layout for fallback ----
#define L_HB_OFF   ((size_t)0)
#define L_FLAG_OFF ((size_t)262144)
#define L_ZROW_OFF ((size_t)264192)
#define L_WS_ZERO  ((size_t)266240)

__device__ __forceinline__ float sigmoidf_(float x) {
    return 1.0f / (1.0f + __expf(-x));
}
__device__ __forceinline__ float tanhf_(float x) {
    return 2.0f * sigmoidf_(2.0f * x) - 1.0f;
}
__device__ __forceinline__ bf16x8 cvt8(const float* p) {
    float4 a = *(const float4*)p;
    float4 b = *(const float4*)(p + 4);
    bf16x8 r;
    r[0] = (bf16)a.x; r[1] = (bf16)a.y; r[2] = (bf16)a.z; r[3] = (bf16)a.w;
    r[4] = (bf16)b.x; r[5] = (bf16)b.y; r[6] = (bf16)b.z; r[7] = (bf16)b.w;
    return r;
}
__device__ __forceinline__ bf16x8 cvt8v(uint4 u0, uint4 u1) {
    float4 a = __builtin_bit_cast(float4, u0);
    float4 b = __builtin_bit_cast(float4, u1);
    bf16x8 r;
    r[0] = (bf16)a.x; r[1] = (bf16)a.y; r[2] = (bf16)a.z; r[3] = (bf16)a.w;
    r[4] = (bf16)b.x; r[5] = (bf16)b.y; r[6] = (bf16)b.z; r[7] = (bf16)b.w;
    return r;
}

__global__ __launch_bounds__(256) void init_scan_ws(unsigned long long* __restrict__ w) {
    const size_t i = (size_t)blockIdx.x * 256 + threadIdx.x;
    if (i < SCAN_ZERO / 8) w[i] = 0ull;
}
__global__ __launch_bounds__(256) void init_ws_legacy(unsigned long long* __restrict__ w) {
    const size_t i = (size_t)blockIdx.x * 256 + threadIdx.x;
    if (i < L_WS_ZERO / 8) w[i] = 0ull;
}

// ---- pre-pass 1: gather + f32->bf16 embedding rows, pad rows zeroed ----
__global__ __launch_bounds__(256) void emb_gather(
    const int* __restrict__ data, const float* __restrict__ table,
    bf16* __restrict__ ebf)
{
    const int wave = threadIdx.x >> 6, lane = threadIdx.x & 63;
    const int rr = blockIdx.x * 4 + wave;          // 0..8191 = t*64+b
    const int qv = data[rr];
    bf16x8 v;
    if (qv >= 0) {
        v = cvt8(table + (size_t)qv * 512 + lane * 8);
    } else {
#pragma unroll
        for (int i = 0; i < 8; ++i) v[i] = (bf16)0.f;
    }
    *(bf16x8*)(ebf + (size_t)rr * 512 + lane * 8) = v;
}

// ---- pre-pass 2: xp = emb @ Wih^T, stored as f32 C-fragments in the scan's
// per-lane layout: xp[((dir*32+kb)*128 + s)*4096 + (wave*64+lane)*16 + t*4 + r]
// grid 1024: dir = bid>>9, kb = (bid>>4)&31, sh = bid&15 (8 steps each).
// kc-ascending MFMA order == scan-side order -> bitwise-stable numerics.
__global__ __launch_bounds__(256, 1) void xproj(
    const bf16* __restrict__ ebf,
    const float* __restrict__ wih_f, const float* __restrict__ wih_b,
    float* __restrict__ xp)
{
    __shared__ bf16 sB[4096 * 8];                  // 64 KB: 64 gate cols x 512 k
    const int tid = threadIdx.x, bid = blockIdx.x;
    const int dir = bid >> 9, kb = (bid >> 4) & 31, sh = bid & 15;
    const int wave = tid >> 6, lane = tid & 63;
    const int c = lane & 15, q = lane >> 4;
    const float* wih = dir ? wih_b : wih_f;

    // stage: entry e = ekc*256 + et*64 + eq*16 + ec; et = tile 0..3
    for (int e = tid; e < 4096; e += 256) {
        const int ec = e & 15, eq = (e >> 4) & 3, et = (e >> 6) & 3, ekc = e >> 8;
        const size_t orig = (size_t)((ec & 3) * 512 + kb * 16 + 4 * (ec >> 2) + et);
        *(bf16x8*)(&sB[e * 8]) = cvt8(&wih[orig * 512 + ekc * 32 + eq * 8]);
    }
    __syncthreads();

    const int hrow = 16 * wave + c;
    const f32x4 zz = {0.f, 0.f, 0.f, 0.f};
    float* xpB = xp + ((size_t)(dir * 32 + kb) * 128) * 4096
               + (size_t)(wave * 64 + lane) * 16;

    for (int s0 = 0; s0 < 8; ++s0) {
        const int s = sh * 8 + s0;
        const int tt = dir ? (127 - s) : s;
        const bf16* arow = ebf + (size_t)(tt * 64 + hrow) * 512;
        uint4 af[16];
#pragma unroll
        for (int kc = 0; kc < 16; ++kc)
            af[kc] = *(const uint4*)(arow + kc * 32 + q * 8);

        f32x4 acc0 = zz, acc1 = zz, acc2 = zz, acc3 = zz;
#pragma unroll
        for (int kc = 0; kc < 16; ++kc) {
            const bf16x8 a = __builtin_bit_cast(bf16x8, af[kc]);
            acc0 = __builtin_amdgcn_mfma_f32_16x16x32_bf16(
                a, *(const bf16x8*)(&sB[(kc * 256 +   0 + q * 16 + c) * 8]), acc0, 0, 0, 0);
            acc1 = __builtin_amdgcn_mfma_f32_16x16x32_bf16(
                a, *(const bf16x8*)(&sB[(kc * 256 +  64 + q * 16 + c) * 8]), acc1, 0, 0, 0);
            acc2 = __builtin_amdgcn_mfma_f32_16x16x32_bf16(
                a, *(const bf16x8*)(&sB[(kc * 256 + 128 + q * 16 + c) * 8]), acc2, 0, 0, 0);
            acc3 = __builtin_amdgcn_mfma_f32_16x16x32_bf16(
                a, *(const bf16x8*)(&sB[(kc * 256 + 192 + q * 16 + c) * 8]), acc3, 0, 0, 0);
        }
        float* dst = xpB + (size_t)s * 4096;
        *(float4*)(dst)      = __builtin_bit_cast(float4, acc0);
        *(float4*)(dst + 4)  = __builtin_bit_cast(float4, acc1);
        *(float4*)(dst + 8)  = __builtin_bit_cast(float4, acc2);
        *(float4*)(dst + 12) = __builtin_bit_cast(float4, acc3);
    }
}

// ---- main persistent scan: XCD-local L2 relay ----
__global__ __launch_bounds__(256, 1) void lstm_scan(
    const float* __restrict__ mask,
    const float* __restrict__ whh_f, const float* __restrict__ whh_b,
    const float* __restrict__ bih_f, const float* __restrict__ bhh_f,
    const float* __restrict__ bih_b, const float* __restrict__ bhh_b,
    const float* __restrict__ xp,
    char* __restrict__ ws,
    float* __restrict__ out)
{
    __shared__ bf16 sW[4096 * 8];      // Whh fragments for 16 units, 64 KB
    __shared__ int s_dir, s_kb;

    const int tid = threadIdx.x;
    const int wave = tid >> 6, lane = tid & 63;
    const int c = lane & 15, q = lane >> 4, g = c & 3;

    // ---- team claim: co-XCD by construction ----
    if (tid == 0) {
        unsigned xcc;
        asm volatile("s_getreg_b32 %0, hwreg(HW_REG_XCC_ID)" : "=s"(xcc));
        const int xcd = (int)(xcc & 7);
        unsigned* cnt  = (unsigned*)(ws + CLAIM_OFF);        // [8]
        unsigned* dirc = (unsigned*)(ws + CLAIM_OFF + 32);
        unsigned* tdir = (unsigned*)(ws + CLAIM_OFF + 36);   // [2]
        const unsigned slot = atomicAdd(&cnt[xcd], 1u);
        const unsigned team = slot >> 5;
        const int kb0 = (int)(slot & 31);
        const unsigned key = (((unsigned)xcd << 8) | team) + 1u;  // 0 = unset
        if (kb0 == 31) {                       // team completer elects
            const unsigned d = atomicAdd(dirc, 1u);
            if (d < 2)
                __hip_atomic_store(&tdir[d], key, __ATOMIC_RELAXED,
                                   __HIP_MEMORY_SCOPE_AGENT);
        }
        int dir = -1;
        for (;;) {
            const unsigned t0 = __hip_atomic_load(&tdir[0], __ATOMIC_RELAXED, __HIP_MEMORY_SCOPE_AGENT);
            const unsigned t1 = __hip_atomic_load(&tdir[1], __ATOMIC_RELAXED, __HIP_MEMORY_SCOPE_AGENT);
            if (t0 == key) { dir = 0; break; }
            if (t1 == key) { dir = 1; break; }
            if (t0 != 0u && t1 != 0u) break;   // both dirs taken elsewhere
            __builtin_amdgcn_s_sleep(8);
        }
        s_dir = dir; s_kb = kb0;
    }
    __syncthreads();
    const int dir = s_dir, kb = s_kb;
    if (dir < 0) return;                        // non-worker block

    const float* whh = dir ? whh_b : whh_f;
    const float* bih = dir ? bih_b : bih_f;
    const float* bhh = dir ? bhh_b : bhh_f;

    // stage Whh fragments (f32 -> bf16, swizzled): 64 gate cols x 512 k
    for (int e = tid; e < 4096; e += 256) {
        const int ec = e & 15, eq = (e >> 4) & 3, et = (e >> 6) & 3, ekc = e >> 8;
        const size_t orig = (size_t)((ec & 3) * 512 + kb * 16 + 4 * (ec >> 2) + et);
        *(bf16x8*)(&sW[e * 8]) = cvt8(&whh[orig * 512 + ekc * 32 + eq * 8]);
    }
    float bias_v[4];
#pragma unroll
    for (int t = 0; t < 4; ++t) {
        const int orig = g * 512 + kb * 16 + 4 * (c >> 2) + t;
        bias_v[t] = bih[orig] + bhh[orig];
    }

    float cst[4][4] = {{0,0,0,0},{0,0,0,0},{0,0,0,0},{0,0,0,0}};
    const int hrow = 16 * wave + c;
    const f32x4 zz = {0.f, 0.f, 0.f, 0.f};

    // flag addresses: idx = dir*128 + wave*32 + kb  (poll: lane&31)
    const unsigned long long f2p = (unsigned long long)(ws + FLAG2_OFF)
        + 4ull * (unsigned)(dir * 128 + wave * 32 + kb);
    const unsigned long long fmp = (unsigned long long)(ws + FLAGM_OFF)
        + 4ull * (unsigned)(dir * 128 + wave * 32 + kb);
    const unsigned long long f2a = (unsigned long long)(ws + FLAG2_OFF)
        + 4ull * (unsigned)(dir * 128 + wave * 32 + (lane & 31));
    const unsigned long long fma_ = (unsigned long long)(ws + FLAGM_OFF)
        + 4ull * (unsigned)(dir * 128 + wave * 32 + (lane & 31));

    char* hrd = ws + HR_OFF + (size_t)dir * HR_DIR;
    __syncthreads();                    // sW ready; no block syncs after this

    // prologue: x-gate fragments + mask for step 0
    const float* xpb = xp + ((size_t)(dir * 32 + kb) * 128) * 4096
                     + (size_t)(wave * 64 + lane) * 16;
    float4 xq[4];
#pragma unroll
    for (int t = 0; t < 4; ++t) xq[t] = *(const float4*)(xpb + t * 4);
    float4 mv;
    {
        const int tt0 = dir ? 127 : 0;
        mv = *(const float4*)(&mask[tt0 * 64 + 16 * wave + 4 * q]);
    }

    for (int s = 0; s < 128; ++s) {
        const int tt = dir ? (127 - s) : s;

        // ---- wait: 32 wave-matched producers completed step s-1.
        // Fast path: sc0 (same-XCD L2). Rescue: sc1 MALL mirror every 8 iters
        // (flags are monotone -> stale sc0 reads only delay, never pass early).
        const unsigned tgt = (unsigned)s;
        {
            unsigned fv; int it = 0;
            for (;;) {
                asm volatile("global_load_dword %0, %1, off sc0\n\t"
                             "s_waitcnt vmcnt(0)"
                             : "=&v"(fv) : "v"(f2a) : "memory");
                if (__all(fv >= tgt)) break;
                if ((++it & 7) == 0) {
                    asm volatile("global_load_dword %0, %1, off sc1\n\t"
                                 "s_waitcnt vmcnt(0)"
                                 : "=&v"(fv) : "v"(fma_) : "memory");
                    if (__all(fv >= tgt)) break;
                }
            }
        }
        __asm__ volatile("" ::: "memory");   // keep h-loads below the poll

        const char* hbS = hrd + (size_t)(s & 7) * HR_STEP;        // h(s-1)
        char*       hwS = hrd + (size_t)((s + 1) & 7) * HR_STEP;  // h(s)

        // ---- h A-fragments: ONE asm node = 16 sc0 dwordx4 + vmcnt(0).
        // Rotating slots => compulsory L1 miss => served by the XCD's L2.
        const unsigned long long ha =
            (unsigned long long)hbS + (unsigned)(hrow * 1024 + q * 16);
        uint4 af[16];
        asm volatile(
            "global_load_dwordx4 %0,  %16, off sc0\n\t"
            "global_load_dwordx4 %1,  %16, off offset:64   sc0\n\t"
            "global_load_dwordx4 %2,  %16, off offset:128  sc0\n\t"
            "global_load_dwordx4 %3,  %16, off offset:192  sc0\n\t"
            "global_load_dwordx4 %4,  %16, off offset:256  sc0\n\t"
            "global_load_dwordx4 %5,  %16, off offset:320  sc0\n\t"
            "global_load_dwordx4 %6,  %16, off offset:384  sc0\n\t"
            "global_load_dwordx4 %7,  %16, off offset:448  sc0\n\t"
            "global_load_dwordx4 %8,  %16, off offset:512  sc0\n\t"
            "global_load_dwordx4 %9,  %16, off offset:576  sc0\n\t"
            "global_load_dwordx4 %10, %16, off offset:640  sc0\n\t"
            "global_load_dwordx4 %11, %16, off offset:704  sc0\n\t"
            "global_load_dwordx4 %12, %16, off offset:768  sc0\n\t"
            "global_load_dwordx4 %13, %16, off offset:832  sc0\n\t"
            "global_load_dwordx4 %14, %16, off offset:896  sc0\n\t"
            "global_load_dwordx4 %15, %16, off offset:960  sc0\n\t"
            "s_waitcnt vmcnt(0)"
            : "=&v"(af[0]),  "=&v"(af[1]),  "=&v"(af[2]),  "=&v"(af[3]),
              "=&v"(af[4]),  "=&v"(af[5]),  "=&v"(af[6]),  "=&v"(af[7]),
              "=&v"(af[8]),  "=&v"(af[9]),  "=&v"(af[10]), "=&v"(af[11]),
              "=&v"(af[12]), "=&v"(af[13]), "=&v"(af[14]), "=&v"(af[15])
            : "v"(ha)
            : "memory");

        f32x4 acc[4] = {zz, zz, zz, zz};
#pragma unroll
        for (int kc = 0; kc < 16; ++kc) {
            const bf16x8 a = __builtin_bit_cast(bf16x8, af[kc]);
#pragma unroll
            for (int t = 0; t < 4; ++t) {
                const bf16x8 b = *(const bf16x8*)(&sW[(kc * 256 + t * 64 + q * 16 + c) * 8]);
                acc[t] = __builtin_amdgcn_mfma_f32_16x16x32_bf16(a, b, acc[t], 0, 0, 0);
            }
        }

        // ---- epilogue: C/D layout col=lane&15, row=q*4+r ----
        float hstore[4][4];                       // [r][t]
#pragma unroll
        for (int r = 0; r < 4; ++r) {
            const int b_ = 16 * wave + 4 * q + r;
            const float m = (&mv.x)[r];
#pragma unroll
            for (int t = 0; t < 4; ++t) {
                float v = acc[t][r] + (&xq[t].x)[r] + bias_v[t];
                const float v1 = __shfl_xor(v, 1);
                const float v2 = __shfl_xor(v, 2);
                const float v3 = __shfl_xor(v, 3);
                const float gi = (g == 0) ? v  : (g == 1) ? v1 : (g == 2) ? v2 : v3;
                const float gf = (g == 0) ? v1 : (g == 1) ? v  : (g == 2) ? v3 : v2;
                const float gG = (g == 0) ? v2 : (g == 1) ? v3 : (g == 2) ? v  : v1;
                const float go = (g == 0) ? v3 : (g == 1) ? v2 : (g == 2) ? v1 : v;
                const float cn = sigmoidf_(gf) * cst[t][r] + sigmoidf_(gi) * tanhf_(gG);
                float hv       = sigmoidf_(go) * tanhf_(cn);
                cst[t][r] = cn * m;               // f32 c-state in registers
                hv *= m;
                hstore[r][t] = hv;
            }
            if (g == 0) {                         // 4 units packed -> 8 B sc0 store
                const unsigned lo =
                    (unsigned)__builtin_bit_cast(unsigned short, (bf16)hstore[r][0]) |
                    ((unsigned)__builtin_bit_cast(unsigned short, (bf16)hstore[r][1]) << 16);
                const unsigned hi =
                    (unsigned)__builtin_bit_cast(unsigned short, (bf16)hstore[r][2]) |
                    ((unsigned)__builtin_bit_cast(unsigned short, (bf16)hstore[r][3]) << 16);
                const unsigned long long du =
                    (unsigned long long)lo | ((unsigned long long)hi << 32);
                const unsigned long long da = (unsigned long long)hwS
                    + (unsigned)(b_ * 1024 + kb * 32 + (c >> 2) * 8);
                asm volatile("global_store_dwordx2 %0, %1, off sc0"
                             :: "v"(da), "v"(du) : "memory");
            }
        }

        // release: all h sc0-stores acked at L2 before flag post
        __asm__ volatile("" ::: "memory");
        __builtin_amdgcn_s_waitcnt(0x0F70);  // vmcnt(0)
        if (lane == 0) {
            unsigned sv = (unsigned)(s + 1);
            asm volatile("global_store_dword %0, %2, off sc0\n\t"
                         "global_store_dword %1, %2, off sc1"
                         :: "v"(f2p), "v"(fmp), "v"(sv) : "memory");
        }

        // ---- step tail (off the relay chain) ----
        if (g == 0) {
            const int j2 = dir * 512 + kb * 16 + 4 * (c >> 2);
#pragma unroll
            for (int r = 0; r < 4; ++r) {
                const int b_ = 16 * wave + 4 * q + r;
                float4 o4;
                o4.x = hstore[r][0]; o4.y = hstore[r][1];
                o4.z = hstore[r][2]; o4.w = hstore[r][3];
                *(float4*)(&out[(size_t)(tt * 64 + b_) * 1024 + j2]) = o4;
            }
        }
        if (s < 127) {
            const int tt_n = dir ? (126 - s) : (s + 1);
            const float* xn = xpb + (size_t)(s + 1) * 4096;
#pragma unroll
            for (int t = 0; t < 4; ++t) xq[t] = *(const float4*)(xn + t * 4);
            mv = *(const float4*)(&mask[tt_n * 64 + 16 * wave + 4 * q]);
        }
    }
}

// ================= verbatim round-9 fallback (ws too small) =================
__global__ __launch_bounds__(256, 1) void lstm_scan_legacy(
    const int*   __restrict__ data,
    const float* __restrict__ mask,
    const float* __restrict__ table,
    const float* __restrict__ wih_f, const float* __restrict__ whh_f,
    const float* __restrict__ bih_f, const float* __restrict__ bhh_f,
    const float* __restrict__ wih_b, const float* __restrict__ whh_b,
    const float* __restrict__ bih_b, const float* __restrict__ bhh_b,
    bf16* __restrict__ hbuf,
    unsigned* __restrict__ flags,
    const float* __restrict__ zrow,
    float* __restrict__ out)
{
    __shared__ bf16 sW[2048 * 8];
    __shared__ bf16 sV[2048 * 8];

    const int tid = threadIdx.x, bid = blockIdx.x;
    const int dir = bid >> 6, kb = bid & 63;
    const int wave = tid >> 6, lane = tid & 63;
    const int c = lane & 15, q = lane >> 4, g = c & 3;

    const float* wih = dir ? wih_b : wih_f;
    const float* whh = dir ? whh_b : whh_f;
    const float* bih = dir ? bih_b : bih_f;
    const float* bhh = dir ? bhh_b : bhh_f;

    for (int e = tid; e < 2048; e += 256) {
        const int ec = e & 15, eq = (e >> 4) & 3, et = (e >> 6) & 1, ekc = e >> 7;
        const size_t orig = (size_t)((ec & 3) * 512 + kb * 8 + 2 * (ec >> 2) + et);
        const size_t off = orig * 512 + ekc * 32 + eq * 8;
        *(bf16x8*)(&sW[e * 8]) = cvt8(&whh[off]);
        *(bf16x8*)(&sV[e * 8]) = cvt8(&wih[off]);
    }
    float bias_v[2];
#pragma unroll
    for (int t4 = 0; t4 < 2; ++t4) {
        const int orig = g * 512 + kb * 8 + 2 * (c >> 2) + t4;
        bias_v[t4] = bih[orig] + bhh[orig];
    }

    float cst[2][4] = {{0.f, 0.f, 0.f, 0.f}, {0.f, 0.f, 0.f, 0.f}};
    const int hrow = 16 * wave + c;
    const int myflag = dir * 256 + kb * 4 + wave;
    const int fbase = dir * 256;
    const f32x4 zz = {0.f, 0.f, 0.f, 0.f};
    __syncthreads();

    uint4 xe[32];
    float4 mv;
    int qv_n;
    {
        const int tt0 = dir ? 127 : 0;
        const int qv0 = data[tt0 * 64 + hrow];
        mv = *(const float4*)(&mask[tt0 * 64 + 16 * wave + 4 * q]);
        const float* erow = (qv0 >= 0) ? (table + (size_t)qv0 * 512) : zrow;
#pragma unroll
        for (int kc = 0; kc < 16; ++kc) {
            xe[2 * kc]     = *(const uint4*)(erow + kc * 32 + q * 8);
            xe[2 * kc + 1] = *(const uint4*)(erow + kc * 32 + q * 8 + 4);
        }
        const int tt1 = dir ? 126 : 1;
        qv_n = data[tt1 * 64 + hrow];
    }

    for (int s = 0; s < 128; ++s) {
        const int tt = dir ? (127 - s) : s;

        f32x4 accx0 = zz, accx1 = zz;
#pragma unroll
        for (int kc = 0; kc < 16; ++kc) {
            const bf16x8 e  = cvt8v(xe[2 * kc], xe[2 * kc + 1]);
            const bf16x8 b0 = *(const bf16x8*)(&sV[(kc * 128 + q * 16 + c) * 8]);
            const bf16x8 b1 = *(const bf16x8*)(&sV[(kc * 128 + 64 + q * 16 + c) * 8]);
            accx0 = __builtin_amdgcn_mfma_f32_16x16x32_bf16(e, b0, accx0, 0, 0, 0);
            accx1 = __builtin_amdgcn_mfma_f32_16x16x32_bf16(e, b1, accx1, 0, 0, 0);
        }

        const unsigned tgt = (unsigned)s;
        for (;;) {
            const unsigned a0 = __hip_atomic_load(flags + fbase + lane,       __ATOMIC_RELAXED, __HIP_MEMORY_SCOPE_AGENT);
            const unsigned a1 = __hip_atomic_load(flags + fbase + 64  + lane, __ATOMIC_RELAXED, __HIP_MEMORY_SCOPE_AGENT);
            const unsigned a2 = __hip_atomic_load(flags + fbase + 128 + lane, __ATOMIC_RELAXED, __HIP_MEMORY_SCOPE_AGENT);
            const unsigned a3 = __hip_atomic_load(flags + fbase + 192 + lane, __ATOMIC_RELAXED, __HIP_MEMORY_SCOPE_AGENT);
            if (__all(a0 >= tgt && a1 >= tgt && a2 >= tgt && a3 >= tgt)) break;
            __builtin_amdgcn_s_sleep(1);
        }
        __asm__ volatile("" ::: "memory");

        const bf16* hb = hbuf + (size_t)(dir * 2 + (s & 1)) * (64 * 512);
        bf16*       hw = hbuf + (size_t)(dir * 2 + ((s + 1) & 1)) * (64 * 512);

        const unsigned long long ha =
            (unsigned long long)hb + (unsigned)(hrow * 1024 + q * 16);
        uint4 af[16];
        asm volatile(
            "global_load_dwordx4 %0,  %16, off sc1\n\t"
            "global_load_dwordx4 %1,  %16, off offset:64   sc1\n\t"
            "global_load_dwordx4 %2,  %16, off offset:128  sc1\n\t"
            "global_load_dwordx4 %3,  %16, off offset:192  sc1\n\t"
            "global_load_dwordx4 %4,  %16, off offset:256  sc1\n\t"
            "global_load_dwordx4 %5,  %16, off offset:320  sc1\n\t"
            "global_load_dwordx4 %6,  %16, off offset:384  sc1\n\t"
            "global_load_dwordx4 %7,  %16, off offset:448  sc1\n\t"
            "global_load_dwordx4 %8,  %16, off offset:512  sc1\n\t"
            "global_load_dwordx4 %9,  %16, off offset:576  sc1\n\t"
            "global_load_dwordx4 %10, %16, off offset:640  sc1\n\t"
            "global_load_dwordx4 %11, %16, off offset:704  sc1\n\t"
            "global_load_dwordx4 %12, %16, off offset:768  sc1\n\t"
            "global_load_dwordx4 %13, %16, off offset:832  sc1\n\t"
            "global_load_dwordx4 %14, %16, off offset:896  sc1\n\t"
            "global_load_dwordx4 %15, %16, off offset:960  sc1\n\t"
            "s_waitcnt vmcnt(0)"
            : "=&v"(af[0]),  "=&v"(af[1]),  "=&v"(af[2]),  "=&v"(af[3]),
              "=&v"(af[4]),  "=&v"(af[5]),  "=&v"(af[6]),  "=&v"(af[7]),
              "=&v"(af[8]),  "=&v"(af[9]),  "=&v"(af[10]), "=&v"(af[11]),
              "=&v"(af[12]), "=&v"(af[13]), "=&v"(af[14]), "=&v"(af[15])
            : "v"(ha)
            : "memory");

        f32x4 acc0 = zz, acc1 = zz;
#pragma unroll
        for (int kc = 0; kc < 16; ++kc) {
            const bf16x8 a  = __builtin_bit_cast(bf16x8, af[kc]);
            const bf16x8 b0 = *(const bf16x8*)(&sW[(kc * 128 + q * 16 + c) * 8]);
            const bf16x8 b1 = *(const bf16x8*)(&sW[(kc * 128 + 64 + q * 16 + c) * 8]);
            acc0 = __builtin_amdgcn_mfma_f32_16x16x32_bf16(a, b0, acc0, 0, 0, 0);
            acc1 = __builtin_amdgcn_mfma_f32_16x16x32_bf16(a, b1, acc1, 0, 0, 0);
        }

        unsigned* hw32 = (unsigned*)hw;
        float hreg[4][2];
#pragma unroll
        for (int r = 0; r < 4; ++r) {
            const int b_ = 16 * wave + 4 * q + r;
            const float m = (&mv.x)[r];
            float hv01[2];
#pragma unroll
            for (int t4 = 0; t4 < 2; ++t4) {
                float v = (t4 ? acc1[r] : acc0[r]) + (t4 ? accx1[r] : accx0[r]) + bias_v[t4];
                const float v1 = __shfl_xor(v, 1);
                const float v2 = __shfl_xor(v, 2);
                const float v3 = __shfl_xor(v, 3);
                const float gi = (g == 0) ? v  : (g == 1) ? v1 : (g == 2) ? v2 : v3;
                const float gf = (g == 0) ? v1 : (g == 1) ? v  : (g == 2) ? v3 : v2;
                const float gG = (g == 0) ? v2 : (g == 1) ? v3 : (g == 2) ? v  : v1;
                const float go = (g == 0) ? v3 : (g == 1) ? v2 : (g == 2) ? v1 : v;
                const float cn = sigmoidf_(gf) * cst[t4][r] + sigmoidf_(gi) * tanhf_(gG);
                float hv       = sigmoidf_(go) * tanhf_(cn);
                cst[t4][r] = cn * m;
                hv *= m;
                hv01[t4] = hv;
            }
            hreg[r][0] = hv01[0]; hreg[r][1] = hv01[1];
            if (g == 0) {
                const unsigned u =
                    (unsigned)__builtin_bit_cast(unsigned short, (bf16)hv01[0]) |
                    ((unsigned)__builtin_bit_cast(unsigned short, (bf16)hv01[1]) << 16);
                __hip_atomic_store(hw32 + b_ * 256 + kb * 4 + (c >> 2), u,
                                   __ATOMIC_RELAXED, __HIP_MEMORY_SCOPE_AGENT);
            }
        }

        __asm__ volatile("" ::: "memory");
        __builtin_amdgcn_s_waitcnt(0x0F70);
        if (lane == 0)
            __hip_atomic_store(flags + myflag, (unsigned)(s + 1),
                               __ATOMIC_RELAXED, __HIP_MEMORY_SCOPE_AGENT);

        if (g == 0) {
            const int j2 = dir * 512 + kb * 8 + 2 * (c >> 2);
#pragma unroll
            for (int r = 0; r < 4; ++r) {
                const int b_ = 16 * wave + 4 * q + r;
                float2 o2; o2.x = hreg[r][0]; o2.y = hreg[r][1];
                *(float2*)(&out[(size_t)(tt * 64 + b_) * 1024 + j2]) = o2;
            }
        }
        if (s < 127) {
            const int tt_n = dir ? (126 - s) : (s + 1);
            const float* erow = (qv_n >= 0) ? (table + (size_t)qv_n * 512) : zrow;
#pragma unroll
            for (int kc = 0; kc < 16; ++kc) {
                xe[2 * kc]     = *(const uint4*)(erow + kc * 32 + q * 8);
                xe[2 * kc + 1] = *(const uint4*)(erow + kc * 32 + q * 8 + 4);
            }
            mv = *(const float4*)(&mask[tt_n * 64 + 16 * wave + 4 * q]);
            if (s < 126) {
                const int tt_n2 = dir ? (125 - s) : (s + 2);
                qv_n = data[tt_n2 * 64 + hrow];
            }
        }
    }
}

extern "C" void kernel_launch(void* const* d_in, const int* in_sizes, int n_in,
                              void* d_out, int out_size, void* d_ws, size_t ws_size,
                              hipStream_t stream) {
    const int*   data  = (const int*)d_in[0];
    const float* mask  = (const float*)d_in[1];
    const float* table = (const float*)d_in[2];
    const float* wih_f = (const float*)d_in[3];
    const float* whh_f = (const float*)d_in[4];
    const float* bih_f = (const float*)d_in[5];
    const float* bhh_f = (const float*)d_in[6];
    const float* wih_b = (const float*)d_in[7];
    const float* whh_b = (const float*)d_in[8];
    const float* bih_b = (const float*)d_in[9];
    const float* bhh_b = (const float*)d_in[10];
    float* outp = (float*)d_out;
    char* ws = (char*)d_ws;

    if (ws_size >= WS_NEED) {
        bf16*  ebf = (bf16*)(ws + EBF_OFF);
        float* xp  = (float*)(ws + XP_OFF);
        emb_gather<<<2048, 256, 0, stream>>>(data, table, ebf);
        xproj<<<1024, 256, 0, stream>>>(ebf, wih_f, wih_b, xp);
        // zero flags/claim/hrot AFTER xproj (region overlays dead ebf)
        init_scan_ws<<<(int)((SCAN_ZERO / 8 + 255) / 256), 256, 0, stream>>>(
            (unsigned long long*)ws);
        lstm_scan<<<1024, 256, 0, stream>>>(mask, whh_f, whh_b,
                                            bih_f, bhh_f, bih_b, bhh_b,
                                            xp, ws, outp);
    } else {
        bf16*       hbuf  = (bf16*)(ws + L_HB_OFF);
        unsigned*   flagp = (unsigned*)(ws + L_FLAG_OFF);
        const float* zrow = (const float*)(ws + L_ZROW_OFF);
        init_ws_legacy<<<(int)((L_WS_ZERO / 8 + 255) / 256), 256, 0, stream>>>(
            (unsigned long long*)ws);
        lstm_scan_legacy<<<128, 256, 0, stream>>>(data, mask, table,
                                                  wih_f, whh_f, bih_f, bhh_f,
                                                  wih_b, whh_b, bih_b, bhh_b,
                                                  hbuf, flagp, zrow, outp);
    }
}

// Round 3
// 1124.550 us; speedup vs baseline: 1.4846x; 1.4846x over previous
//
#include <hip/hip_runtime.h>

// NLReader bidirectional LSTM, MI355X — persistent scan, fence-free MALL relay.
//
// Round-12 = round-10's scan (measured 857 us dispatch) + round-11's prepass
// tiling (measured ~90 us bench-vs-scan gap vs round-10's ~350 us).
//  * lstm_scan: VERBATIM round-10. 128 blocks x 256 thr, 8 units/block,
//    wave-matched flags (consumer wave w polls its 64 wave-w producers, one
//    load/lane), agent-scope (sc1, MALL) h relay, one-asm-node h-fetch,
//    f32 c-state in registers, x-projection fully precomputed.
//  * xproj: round-10 OUTPUT LAYOUT (xp[(dir*64+kb)*128 + s][2048], 8-unit
//    blocks) with round-11 GRID (1024 blocks = dir x cc(32) x sh(16), 8 steps
//    each) -> prepass no longer serializes at 2 waves/CU.
//  * emb_gather: folds the 266 KB scan-region zeroing into blocks 0..129
//    (one less launch).
//  * Round-11's XCD-local sc0 relay REVERTED: it regressed 857->1580 us
//    (single-L2 flag-line hotspot beats any latency saving).
//
// Block (dir=bid>>6, kb=bid&63) owns 8 hidden units as 32 permuted gate cols:
//   tile t4 in {0,1}, lane col c in [0,16): gate g = c&3, unit jj = 2*(c>>2)+t4
//   orig Wih/Whh row = g*512 + kb*8 + jj.

typedef float  f32x4  __attribute__((ext_vector_type(4)));
typedef __bf16 bf16x8 __attribute__((ext_vector_type(8)));
typedef __bf16 bf16;

#define HB_OFF   ((size_t)0)        // 4 x [64 x 512] bf16 = 262144 B
#define FLAG_OFF ((size_t)262144)   // 512 x u32 = 2048 B
#define ZROW_OFF ((size_t)264192)   // 512 f32 zero row (legacy path only)
#define WS_ZERO_BYTES ((size_t)266240)
#define XP_OFF   ((size_t)266240)                 // 128 blk*128 s*2048 f32
#define XP_BYTES ((size_t)134217728)
#define EBF_OFF  (XP_OFF + XP_BYTES)              // 8192 rows * 512 bf16
#define EBF_BYTES ((size_t)8388608)
#define WS_NEED  (EBF_OFF + EBF_BYTES)            // 142,872,576 B

__device__ __forceinline__ float sigmoidf_(float x) {
    return 1.0f / (1.0f + __expf(-x));
}
__device__ __forceinline__ float tanhf_(float x) {
    return 2.0f * sigmoidf_(2.0f * x) - 1.0f;
}
__device__ __forceinline__ bf16x8 cvt8(const float* p) {
    float4 a = *(const float4*)p;
    float4 b = *(const float4*)(p + 4);
    bf16x8 r;
    r[0] = (bf16)a.x; r[1] = (bf16)a.y; r[2] = (bf16)a.z; r[3] = (bf16)a.w;
    r[4] = (bf16)b.x; r[5] = (bf16)b.y; r[6] = (bf16)b.z; r[7] = (bf16)b.w;
    return r;
}
__device__ __forceinline__ bf16x8 cvt8v(uint4 u0, uint4 u1) {
    float4 a = __builtin_bit_cast(float4, u0);
    float4 b = __builtin_bit_cast(float4, u1);
    bf16x8 r;
    r[0] = (bf16)a.x; r[1] = (bf16)a.y; r[2] = (bf16)a.z; r[3] = (bf16)a.w;
    r[4] = (bf16)b.x; r[5] = (bf16)b.y; r[6] = (bf16)b.z; r[7] = (bf16)b.w;
    return r;
}

__global__ __launch_bounds__(256) void init_ws_legacy(unsigned long long* __restrict__ w) {
    const size_t i = (size_t)blockIdx.x * 256 + threadIdx.x;
    if (i < WS_ZERO_BYTES / 8) w[i] = 0ull;
}

// ---- pre-pass 1: gather + f32->bf16 embedding rows; pad rows zeroed.
// Blocks 0..129 also zero the 266 KB scan region (hbuf+flags+zrow).
// grid 2048 x 256 (one wave per row).
__global__ __launch_bounds__(256) void emb_gather(
    const int* __restrict__ data, const float* __restrict__ table,
    bf16* __restrict__ ebf, unsigned long long* __restrict__ wz)
{
    const int bid = blockIdx.x, tid = threadIdx.x;
    if (bid < 130) {                                // 130*256*8 = 266240 B
        wz[(size_t)bid * 256 + tid] = 0ull;
    }
    const int wave = tid >> 6, lane = tid & 63;
    const int rr = bid * 4 + wave;                  // 0..8191 = t*64+b
    const int qv = data[rr];
    bf16x8 v;
    if (qv >= 0) {
        v = cvt8(table + (size_t)qv * 512 + lane * 8);
    } else {
#pragma unroll
        for (int i = 0; i < 8; ++i) v[i] = (bf16)0.f;
    }
    *(bf16x8*)(ebf + (size_t)rr * 512 + lane * 8) = v;
}

// ---- pre-pass 2: xp = emb @ Wih^T for all steps, stored as f32 C-fragments
// in the scan's per-lane layout:
//   xp[((dir*64+kb)*128 + s)*2048 + wave*512 + (q*16+c)*8 + t4*4 + r]
// grid 1024 x 256: dir = bid>>9, cc = (bid>>4)&31 (covers kb 2cc,2cc+1),
// sh = bid&15 (8-step group). kc-ascending MFMA order == round-9 in-loop
// order -> bitwise-stable numerics.
__global__ __launch_bounds__(256, 1) void xproj(
    const bf16* __restrict__ ebf,
    const float* __restrict__ wih_f, const float* __restrict__ wih_b,
    float* __restrict__ xp)
{
    __shared__ bf16 sB[4096 * 8];                  // 64 KB: 64 gate cols x 512 k
    const int tid = threadIdx.x, bid = blockIdx.x;
    const int dir = bid >> 9, cc = (bid >> 4) & 31, sh = bid & 15;
    const int wave = tid >> 6, lane = tid & 63;
    const int c = lane & 15, q = lane >> 4;
    const float* wih = dir ? wih_b : wih_f;

    // stage: entry e = ekc*256 + et*64 + eq*16 + ec; et = col tile 0..3
    for (int e = tid; e < 4096; e += 256) {
        const int ec = e & 15, eq = (e >> 4) & 3, et = (e >> 6) & 3, ekc = e >> 8;
        const int kbx = 2 * cc + (et >> 1), t4x = et & 1;
        const size_t orig = (size_t)((ec & 3) * 512 + kbx * 8 + 2 * (ec >> 2) + t4x);
        *(bf16x8*)(&sB[e * 8]) = cvt8(&wih[orig * 512 + ekc * 32 + eq * 8]);
    }
    __syncthreads();

    const int hrow = 16 * wave + c;
    const f32x4 zz = {0.f, 0.f, 0.f, 0.f};
    const size_t flin = (size_t)wave * 512 + (q * 16 + c) * 8;

    for (int s0 = 0; s0 < 8; ++s0) {
        const int s = sh * 8 + s0;
        const int tt = dir ? (127 - s) : s;
        const bf16* arow = ebf + (size_t)(tt * 64 + hrow) * 512;
        uint4 af[16];
#pragma unroll
        for (int kc = 0; kc < 16; ++kc)
            af[kc] = *(const uint4*)(arow + kc * 32 + q * 8);

        f32x4 acc0 = zz, acc1 = zz, acc2 = zz, acc3 = zz;
#pragma unroll
        for (int kc = 0; kc < 16; ++kc) {
            const bf16x8 a = __builtin_bit_cast(bf16x8, af[kc]);
            acc0 = __builtin_amdgcn_mfma_f32_16x16x32_bf16(
                a, *(const bf16x8*)(&sB[(kc * 256 +   0 + q * 16 + c) * 8]), acc0, 0, 0, 0);
            acc1 = __builtin_amdgcn_mfma_f32_16x16x32_bf16(
                a, *(const bf16x8*)(&sB[(kc * 256 +  64 + q * 16 + c) * 8]), acc1, 0, 0, 0);
            acc2 = __builtin_amdgcn_mfma_f32_16x16x32_bf16(
                a, *(const bf16x8*)(&sB[(kc * 256 + 128 + q * 16 + c) * 8]), acc2, 0, 0, 0);
            acc3 = __builtin_amdgcn_mfma_f32_16x16x32_bf16(
                a, *(const bf16x8*)(&sB[(kc * 256 + 192 + q * 16 + c) * 8]), acc3, 0, 0, 0);
        }
        const size_t r0 = ((size_t)(dir * 64 + 2 * cc)     * 128 + s) * 2048 + flin;
        const size_t r1 = ((size_t)(dir * 64 + 2 * cc + 1) * 128 + s) * 2048 + flin;
        *(float4*)(&xp[r0])     = __builtin_bit_cast(float4, acc0);   // kb=2cc,  t4=0
        *(float4*)(&xp[r0 + 4]) = __builtin_bit_cast(float4, acc1);   // kb=2cc,  t4=1
        *(float4*)(&xp[r1])     = __builtin_bit_cast(float4, acc2);   // kb=2cc+1,t4=0
        *(float4*)(&xp[r1 + 4]) = __builtin_bit_cast(float4, acc3);   // kb=2cc+1,t4=1
    }
}

// ---- main persistent scan (verbatim round-10, measured 857 us) ----
// flag index = dir*256 + wave*64 + kb (consumer wave w polls its 64 wave-w
// producers in one contiguous 256 B region: 1 load/lane).
__global__ __launch_bounds__(256, 1) void lstm_scan(
    const float* __restrict__ mask,    // [128,64] f32 (0/1)
    const float* __restrict__ whh_f, const float* __restrict__ whh_b,
    const float* __restrict__ bih_f, const float* __restrict__ bhh_f,
    const float* __restrict__ bih_b, const float* __restrict__ bhh_b,
    const float* __restrict__ xp,      // precomputed x-gate fragments
    bf16* __restrict__ hbuf,           // [dir][buf][64][512] bf16 (internal)
    unsigned* __restrict__ flags,      // 512 per-wave monotone flags
    float* __restrict__ out)           // [128,64,1024] f32
{
    __shared__ bf16 sW[2048 * 8];      // Whh fragments, 32 KB

    const int tid = threadIdx.x, bid = blockIdx.x;
    const int dir = bid >> 6, kb = bid & 63;
    const int wave = tid >> 6, lane = tid & 63;
    const int c = lane & 15, q = lane >> 4, g = c & 3;

    const float* whh = dir ? whh_b : whh_f;
    const float* bih = dir ? bih_b : bih_f;
    const float* bhh = dir ? bhh_b : bhh_f;

    for (int e = tid; e < 2048; e += 256) {
        const int ec = e & 15, eq = (e >> 4) & 3, et = (e >> 6) & 1, ekc = e >> 7;
        const size_t orig = (size_t)((ec & 3) * 512 + kb * 8 + 2 * (ec >> 2) + et);
        *(bf16x8*)(&sW[e * 8]) = cvt8(&whh[orig * 512 + ekc * 32 + eq * 8]);
    }
    float bias_v[2];
#pragma unroll
    for (int t4 = 0; t4 < 2; ++t4) {
        const int orig = g * 512 + kb * 8 + 2 * (c >> 2) + t4;
        bias_v[t4] = bih[orig] + bhh[orig];
    }

    float cst[2][4] = {{0.f, 0.f, 0.f, 0.f}, {0.f, 0.f, 0.f, 0.f}};
    const int hrow = 16 * wave + c;
    const int myflag = dir * 256 + wave * 64 + kb;
    const int fidx   = dir * 256 + wave * 64 + lane;
    const f32x4 zz = {0.f, 0.f, 0.f, 0.f};
    __syncthreads();                    // sW ready; no syncs after this

    // prologue: x-gate fragment + mask for step 0
    const float* xpb = xp + (size_t)bid * 128 * 2048
                          + (size_t)wave * 512 + (q * 16 + c) * 8;
    float4 xq0 = *(const float4*)(xpb);
    float4 xq1 = *(const float4*)(xpb + 4);
    float4 mv;
    {
        const int tt0 = dir ? 127 : 0;
        mv = *(const float4*)(&mask[tt0 * 64 + 16 * wave + 4 * q]);
    }

    for (int s = 0; s < 128; ++s) {
        const int tt = dir ? (127 - s) : s;

        // ---- wait: the 64 wave-matched producer waves completed step s-1.
        // Software-pipelined: one flag load in flight while testing the last.
        const unsigned tgt = (unsigned)s;
        unsigned fa = __hip_atomic_load(flags + fidx, __ATOMIC_RELAXED, __HIP_MEMORY_SCOPE_AGENT);
        unsigned fb = __hip_atomic_load(flags + fidx, __ATOMIC_RELAXED, __HIP_MEMORY_SCOPE_AGENT);
        for (;;) {
            if (__all(fa >= tgt)) break;
            fa = fb;
            fb = __hip_atomic_load(flags + fidx, __ATOMIC_RELAXED, __HIP_MEMORY_SCOPE_AGENT);
        }
        __asm__ volatile("" ::: "memory");   // keep h-loads below the poll

        const bf16* hb = hbuf + (size_t)(dir * 2 + (s & 1)) * (64 * 512);
        bf16*       hw = hbuf + (size_t)(dir * 2 + ((s + 1) & 1)) * (64 * 512);

        // ---- h A-fragments: ONE asm node = 16 agent-scope (sc1) dwordx4
        //      loads + s_waitcnt vmcnt(0); "=&v" keeps dests off the addr pair.
        const unsigned long long ha =
            (unsigned long long)hb + (unsigned)(hrow * 1024 + q * 16);
        uint4 af[16];
        asm volatile(
            "global_load_dwordx4 %0,  %16, off sc1\n\t"
            "global_load_dwordx4 %1,  %16, off offset:64   sc1\n\t"
            "global_load_dwordx4 %2,  %16, off offset:128  sc1\n\t"
            "global_load_dwordx4 %3,  %16, off offset:192  sc1\n\t"
            "global_load_dwordx4 %4,  %16, off offset:256  sc1\n\t"
            "global_load_dwordx4 %5,  %16, off offset:320  sc1\n\t"
            "global_load_dwordx4 %6,  %16, off offset:384  sc1\n\t"
            "global_load_dwordx4 %7,  %16, off offset:448  sc1\n\t"
            "global_load_dwordx4 %8,  %16, off offset:512  sc1\n\t"
            "global_load_dwordx4 %9,  %16, off offset:576  sc1\n\t"
            "global_load_dwordx4 %10, %16, off offset:640  sc1\n\t"
            "global_load_dwordx4 %11, %16, off offset:704  sc1\n\t"
            "global_load_dwordx4 %12, %16, off offset:768  sc1\n\t"
            "global_load_dwordx4 %13, %16, off offset:832  sc1\n\t"
            "global_load_dwordx4 %14, %16, off offset:896  sc1\n\t"
            "global_load_dwordx4 %15, %16, off offset:960  sc1\n\t"
            "s_waitcnt vmcnt(0)"
            : "=&v"(af[0]),  "=&v"(af[1]),  "=&v"(af[2]),  "=&v"(af[3]),
              "=&v"(af[4]),  "=&v"(af[5]),  "=&v"(af[6]),  "=&v"(af[7]),
              "=&v"(af[8]),  "=&v"(af[9]),  "=&v"(af[10]), "=&v"(af[11]),
              "=&v"(af[12]), "=&v"(af[13]), "=&v"(af[14]), "=&v"(af[15])
            : "v"(ha)
            : "memory");

        f32x4 acc0 = zz, acc1 = zz;
#pragma unroll
        for (int kc = 0; kc < 16; ++kc) {
            const bf16x8 a  = __builtin_bit_cast(bf16x8, af[kc]);
            const bf16x8 b0 = *(const bf16x8*)(&sW[(kc * 128 + q * 16 + c) * 8]);
            const bf16x8 b1 = *(const bf16x8*)(&sW[(kc * 128 + 64 + q * 16 + c) * 8]);
            acc0 = __builtin_amdgcn_mfma_f32_16x16x32_bf16(a, b0, acc0, 0, 0, 0);
            acc1 = __builtin_amdgcn_mfma_f32_16x16x32_bf16(a, b1, acc1, 0, 0, 0);
        }

        // ---- epilogue: C/D layout col=lane&15, row=q*4+r ----
        unsigned* hw32 = (unsigned*)hw;
        float hreg[4][2];
#pragma unroll
        for (int r = 0; r < 4; ++r) {
            const int b_ = 16 * wave + 4 * q + r;
            const float m = (&mv.x)[r];
            float hv01[2];
#pragma unroll
            for (int t4 = 0; t4 < 2; ++t4) {
                float v = (t4 ? acc1[r] : acc0[r])
                        + (t4 ? (&xq1.x)[r] : (&xq0.x)[r]) + bias_v[t4];
                const float v1 = __shfl_xor(v, 1);
                const float v2 = __shfl_xor(v, 2);
                const float v3 = __shfl_xor(v, 3);
                const float gi = (g == 0) ? v  : (g == 1) ? v1 : (g == 2) ? v2 : v3;
                const float gf = (g == 0) ? v1 : (g == 1) ? v  : (g == 2) ? v3 : v2;
                const float gG = (g == 0) ? v2 : (g == 1) ? v3 : (g == 2) ? v  : v1;
                const float go = (g == 0) ? v3 : (g == 1) ? v2 : (g == 2) ? v1 : v;
                const float cn = sigmoidf_(gf) * cst[t4][r] + sigmoidf_(gi) * tanhf_(gG);
                float hv       = sigmoidf_(go) * tanhf_(cn);
                cst[t4][r] = cn * m;
                hv *= m;
                hv01[t4] = hv;
            }
            hreg[r][0] = hv01[0]; hreg[r][1] = hv01[1];
            if (g == 0) {                   // packed 2xbf16 -> one u32 sc1 store
                const unsigned u =
                    (unsigned)__builtin_bit_cast(unsigned short, (bf16)hv01[0]) |
                    ((unsigned)__builtin_bit_cast(unsigned short, (bf16)hv01[1]) << 16);
                __hip_atomic_store(hw32 + b_ * 256 + kb * 4 + (c >> 2), u,
                                   __ATOMIC_RELAXED, __HIP_MEMORY_SCOPE_AGENT);
            }
        }

        // release: all h sc1-stores acked at MALL before flag store
        __asm__ volatile("" ::: "memory");
        __builtin_amdgcn_s_waitcnt(0x0F70);  // vmcnt(0)
        if (lane == 0)
            __hip_atomic_store(flags + myflag, (unsigned)(s + 1),
                               __ATOMIC_RELAXED, __HIP_MEMORY_SCOPE_AGENT);

        // ---- step tail (hidden behind other blocks' consumption) ----
        if (g == 0) {
            const int j2 = dir * 512 + kb * 8 + 2 * (c >> 2);
#pragma unroll
            for (int r = 0; r < 4; ++r) {
                const int b_ = 16 * wave + 4 * q + r;
                float2 o2; o2.x = hreg[r][0]; o2.y = hreg[r][1];
                *(float2*)(&out[(size_t)(tt * 64 + b_) * 1024 + j2]) = o2;
            }
        }
        if (s < 127) {
            const int tt_n = dir ? (126 - s) : (s + 1);
            xq0 = *(const float4*)(xpb + (size_t)(s + 1) * 2048);
            xq1 = *(const float4*)(xpb + (size_t)(s + 1) * 2048 + 4);
            mv  = *(const float4*)(&mask[tt_n * 64 + 16 * wave + 4 * q]);
        }
    }
}

// ================= verbatim round-9 fallback (ws too small) =================
__global__ __launch_bounds__(256, 1) void lstm_scan_legacy(
    const int*   __restrict__ data,
    const float* __restrict__ mask,
    const float* __restrict__ table,
    const float* __restrict__ wih_f, const float* __restrict__ whh_f,
    const float* __restrict__ bih_f, const float* __restrict__ bhh_f,
    const float* __restrict__ wih_b, const float* __restrict__ whh_b,
    const float* __restrict__ bih_b, const float* __restrict__ bhh_b,
    bf16* __restrict__ hbuf,
    unsigned* __restrict__ flags,
    const float* __restrict__ zrow,
    float* __restrict__ out)
{
    __shared__ bf16 sW[2048 * 8];
    __shared__ bf16 sV[2048 * 8];

    const int tid = threadIdx.x, bid = blockIdx.x;
    const int dir = bid >> 6, kb = bid & 63;
    const int wave = tid >> 6, lane = tid & 63;
    const int c = lane & 15, q = lane >> 4, g = c & 3;

    const float* wih = dir ? wih_b : wih_f;
    const float* whh = dir ? whh_b : whh_f;
    const float* bih = dir ? bih_b : bih_f;
    const float* bhh = dir ? bhh_b : bhh_f;

    for (int e = tid; e < 2048; e += 256) {
        const int ec = e & 15, eq = (e >> 4) & 3, et = (e >> 6) & 1, ekc = e >> 7;
        const size_t orig = (size_t)((ec & 3) * 512 + kb * 8 + 2 * (ec >> 2) + et);
        const size_t off = orig * 512 + ekc * 32 + eq * 8;
        *(bf16x8*)(&sW[e * 8]) = cvt8(&whh[off]);
        *(bf16x8*)(&sV[e * 8]) = cvt8(&wih[off]);
    }
    float bias_v[2];
#pragma unroll
    for (int t4 = 0; t4 < 2; ++t4) {
        const int orig = g * 512 + kb * 8 + 2 * (c >> 2) + t4;
        bias_v[t4] = bih[orig] + bhh[orig];
    }

    float cst[2][4] = {{0.f, 0.f, 0.f, 0.f}, {0.f, 0.f, 0.f, 0.f}};
    const int hrow = 16 * wave + c;
    const int myflag = dir * 256 + kb * 4 + wave;
    const int fbase = dir * 256;
    const f32x4 zz = {0.f, 0.f, 0.f, 0.f};
    __syncthreads();

    uint4 xe[32];
    float4 mv;
    int qv_n;
    {
        const int tt0 = dir ? 127 : 0;
        const int qv0 = data[tt0 * 64 + hrow];
        mv = *(const float4*)(&mask[tt0 * 64 + 16 * wave + 4 * q]);
        const float* erow = (qv0 >= 0) ? (table + (size_t)qv0 * 512) : zrow;
#pragma unroll
        for (int kc = 0; kc < 16; ++kc) {
            xe[2 * kc]     = *(const uint4*)(erow + kc * 32 + q * 8);
            xe[2 * kc + 1] = *(const uint4*)(erow + kc * 32 + q * 8 + 4);
        }
        const int tt1 = dir ? 126 : 1;
        qv_n = data[tt1 * 64 + hrow];
    }

    for (int s = 0; s < 128; ++s) {
        const int tt = dir ? (127 - s) : s;

        f32x4 accx0 = zz, accx1 = zz;
#pragma unroll
        for (int kc = 0; kc < 16; ++kc) {
            const bf16x8 e  = cvt8v(xe[2 * kc], xe[2 * kc + 1]);
            const bf16x8 b0 = *(const bf16x8*)(&sV[(kc * 128 + q * 16 + c) * 8]);
            const bf16x8 b1 = *(const bf16x8*)(&sV[(kc * 128 + 64 + q * 16 + c) * 8]);
            accx0 = __builtin_amdgcn_mfma_f32_16x16x32_bf16(e, b0, accx0, 0, 0, 0);
            accx1 = __builtin_amdgcn_mfma_f32_16x16x32_bf16(e, b1, accx1, 0, 0, 0);
        }

        const unsigned tgt = (unsigned)s;
        for (;;) {
            const unsigned a0 = __hip_atomic_load(flags + fbase + lane,       __ATOMIC_RELAXED, __HIP_MEMORY_SCOPE_AGENT);
            const unsigned a1 = __hip_atomic_load(flags + fbase + 64  + lane, __ATOMIC_RELAXED, __HIP_MEMORY_SCOPE_AGENT);
            const unsigned a2 = __hip_atomic_load(flags + fbase + 128 + lane, __ATOMIC_RELAXED, __HIP_MEMORY_SCOPE_AGENT);
            const unsigned a3 = __hip_atomic_load(flags + fbase + 192 + lane, __ATOMIC_RELAXED, __HIP_MEMORY_SCOPE_AGENT);
            if (__all(a0 >= tgt && a1 >= tgt && a2 >= tgt && a3 >= tgt)) break;
            __builtin_amdgcn_s_sleep(1);
        }
        __asm__ volatile("" ::: "memory");

        const bf16* hb = hbuf + (size_t)(dir * 2 + (s & 1)) * (64 * 512);
        bf16*       hw = hbuf + (size_t)(dir * 2 + ((s + 1) & 1)) * (64 * 512);

        const unsigned long long ha =
            (unsigned long long)hb + (unsigned)(hrow * 1024 + q * 16);
        uint4 af[16];
        asm volatile(
            "global_load_dwordx4 %0,  %16, off sc1\n\t"
            "global_load_dwordx4 %1,  %16, off offset:64   sc1\n\t"
            "global_load_dwordx4 %2,  %16, off offset:128  sc1\n\t"
            "global_load_dwordx4 %3,  %16, off offset:192  sc1\n\t"
            "global_load_dwordx4 %4,  %16, off offset:256  sc1\n\t"
            "global_load_dwordx4 %5,  %16, off offset:320  sc1\n\t"
            "global_load_dwordx4 %6,  %16, off offset:384  sc1\n\t"
            "global_load_dwordx4 %7,  %16, off offset:448  sc1\n\t"
            "global_load_dwordx4 %8,  %16, off offset:512  sc1\n\t"
            "global_load_dwordx4 %9,  %16, off offset:576  sc1\n\t"
            "global_load_dwordx4 %10, %16, off offset:640  sc1\n\t"
            "global_load_dwordx4 %11, %16, off offset:704  sc1\n\t"
            "global_load_dwordx4 %12, %16, off offset:768  sc1\n\t"
            "global_load_dwordx4 %13, %16, off offset:832  sc1\n\t"
            "global_load_dwordx4 %14, %16, off offset:896  sc1\n\t"
            "global_load_dwordx4 %15, %16, off offset:960  sc1\n\t"
            "s_waitcnt vmcnt(0)"
            : "=&v"(af[0]),  "=&v"(af[1]),  "=&v"(af[2]),  "=&v"(af[3]),
              "=&v"(af[4]),  "=&v"(af[5]),  "=&v"(af[6]),  "=&v"(af[7]),
              "=&v"(af[8]),  "=&v"(af[9]),  "=&v"(af[10]), "=&v"(af[11]),
              "=&v"(af[12]), "=&v"(af[13]), "=&v"(af[14]), "=&v"(af[15])
            : "v"(ha)
            : "memory");

        f32x4 acc0 = zz, acc1 = zz;
#pragma unroll
        for (int kc = 0; kc < 16; ++kc) {
            const bf16x8 a  = __builtin_bit_cast(bf16x8, af[kc]);
            const bf16x8 b0 = *(const bf16x8*)(&sW[(kc * 128 + q * 16 + c) * 8]);
            const bf16x8 b1 = *(const bf16x8*)(&sW[(kc * 128 + 64 + q * 16 + c) * 8]);
            acc0 = __builtin_amdgcn_mfma_f32_16x16x32_bf16(a, b0, acc0, 0, 0, 0);
            acc1 = __builtin_amdgcn_mfma_f32_16x16x32_bf16(a, b1, acc1, 0, 0, 0);
        }

        unsigned* hw32 = (unsigned*)hw;
        float hreg[4][2];
#pragma unroll
        for (int r = 0; r < 4; ++r) {
            const int b_ = 16 * wave + 4 * q + r;
            const float m = (&mv.x)[r];
            float hv01[2];
#pragma unroll
            for (int t4 = 0; t4 < 2; ++t4) {
                float v = (t4 ? acc1[r] : acc0[r]) + (t4 ? accx1[r] : accx0[r]) + bias_v[t4];
                const float v1 = __shfl_xor(v, 1);
                const float v2 = __shfl_xor(v, 2);
                const float v3 = __shfl_xor(v, 3);
                const float gi = (g == 0) ? v  : (g == 1) ? v1 : (g == 2) ? v2 : v3;
                const float gf = (g == 0) ? v1 : (g == 1) ? v  : (g == 2) ? v3 : v2;
                const float gG = (g == 0) ? v2 : (g == 1) ? v3 : (g == 2) ? v  : v1;
                const float go = (g == 0) ? v3 : (g == 1) ? v2 : (g == 2) ? v1 : v;
                const float cn = sigmoidf_(gf) * cst[t4][r] + sigmoidf_(gi) * tanhf_(gG);
                float hv       = sigmoidf_(go) * tanhf_(cn);
                cst[t4][r] = cn * m;
                hv *= m;
                hv01[t4] = hv;
            }
            hreg[r][0] = hv01[0]; hreg[r][1] = hv01[1];
            if (g == 0) {
                const unsigned u =
                    (unsigned)__builtin_bit_cast(unsigned short, (bf16)hv01[0]) |
                    ((unsigned)__builtin_bit_cast(unsigned short, (bf16)hv01[1]) << 16);
                __hip_atomic_store(hw32 + b_ * 256 + kb * 4 + (c >> 2), u,
                                   __ATOMIC_RELAXED, __HIP_MEMORY_SCOPE_AGENT);
            }
        }

        __asm__ volatile("" ::: "memory");
        __builtin_amdgcn_s_waitcnt(0x0F70);
        if (lane == 0)
            __hip_atomic_store(flags + myflag, (unsigned)(s + 1),
                               __ATOMIC_RELAXED, __HIP_MEMORY_SCOPE_AGENT);

        if (g == 0) {
            const int j2 = dir * 512 + kb * 8 + 2 * (c >> 2);
#pragma unroll
            for (int r = 0; r < 4; ++r) {
                const int b_ = 16 * wave + 4 * q + r;
                float2 o2; o2.x = hreg[r][0]; o2.y = hreg[r][1];
                *(float2*)(&out[(size_t)(tt * 64 + b_) * 1024 + j2]) = o2;
            }
        }
        if (s < 127) {
            const int tt_n = dir ? (126 - s) : (s + 1);
            const float* erow = (qv_n >= 0) ? (table + (size_t)qv_n * 512) : zrow;
#pragma unroll
            for (int kc = 0; kc < 16; ++kc) {
                xe[2 * kc]     = *(const uint4*)(erow + kc * 32 + q * 8);
                xe[2 * kc + 1] = *(const uint4*)(erow + kc * 32 + q * 8 + 4);
            }
            mv = *(const float4*)(&mask[tt_n * 64 + 16 * wave + 4 * q]);
            if (s < 126) {
                const int tt_n2 = dir ? (125 - s) : (s + 2);
                qv_n = data[tt_n2 * 64 + hrow];
            }
        }
    }
}

extern "C" void kernel_launch(void* const* d_in, const int* in_sizes, int n_in,
                              void* d_out, int out_size, void* d_ws, size_t ws_size,
                              hipStream_t stream) {
    const int*   data  = (const int*)d_in[0];
    const float* mask  = (const float*)d_in[1];
    const float* table = (const float*)d_in[2];
    const float* wih_f = (const float*)d_in[3];
    const float* whh_f = (const float*)d_in[4];
    const float* bih_f = (const float*)d_in[5];
    const float* bhh_f = (const float*)d_in[6];
    const float* wih_b = (const float*)d_in[7];
    const float* whh_b = (const float*)d_in[8];
    const float* bih_b = (const float*)d_in[9];
    const float* bhh_b = (const float*)d_in[10];
    float* outp = (float*)d_out;

    char* ws = (char*)d_ws;
    bf16*     hbuf  = (bf16*)(ws + HB_OFF);
    unsigned* flagp = (unsigned*)(ws + FLAG_OFF);

    if (ws_size >= WS_NEED) {
        bf16*  ebf = (bf16*)(ws + EBF_OFF);
        float* xp  = (float*)(ws + XP_OFF);
        emb_gather<<<2048, 256, 0, stream>>>(data, table, ebf,
                                             (unsigned long long*)ws);
        xproj<<<1024, 256, 0, stream>>>(ebf, wih_f, wih_b, xp);
        lstm_scan<<<128, 256, 0, stream>>>(mask, whh_f, whh_b,
                                           bih_f, bhh_f, bih_b, bhh_b,
                                           xp, hbuf, flagp, outp);
    } else {
        const float* zrow = (const float*)(ws + ZROW_OFF);
        init_ws_legacy<<<(int)((WS_ZERO_BYTES / 8 + 255) / 256), 256, 0, stream>>>(
            (unsigned long long*)ws);
        lstm_scan_legacy<<<128, 256, 0, stream>>>(data, mask, table,
                                                  wih_f, whh_f, bih_f, bhh_f,
                                                  wih_b, whh_b, bih_b, bhh_b,
                                                  hbuf, flagp, zrow, outp);
    }
}

// Round 4
// 1017.130 us; speedup vs baseline: 1.6414x; 1.1056x over previous
//
#include <hip/hip_runtime.h>

// NLReader bidirectional LSTM, MI355X — persistent scan, fence-free MALL relay.
//
// Round-13: xproj prepass FUSED into the scan kernel so its ~200 us of
// bandwidth-bound work hides under the scan's 858 us of ~3%-BW execution.
//  * Grid 1152: bid<128 = scan role (dispatched first, spreads over CUs);
//    bid>=128 = xproj role (dir x cc(32) x sh(16), 8 steps each).
//  * xproj stores xp with sc1 (write-through to MALL — same mechanism as the
//    proven h-relay), per-wave vmcnt(0) ack, __syncthreads, then posts a u16
//    group flag (1024 flags in the legacy-only ZROW bytes; WS_NEED unchanged).
//  * scan polls the group flag only at prologue and every 8th step tail, and
//    loads xq with sc1 asm loads (tail, latency-hidden) so no L1/L2 line can
//    be touched pre-flag (prefetch-staleness hazard eliminated).
//  * Deadlock-free: xproj never waits on scan; scan blocks spin but xproj
//    blocks become resident as others retire; worst case = full serialization
//    (round-12 behavior), no hang.
//  * scan role itself VERBATIM round-10/12 (measured 858 us): wave-matched
//    flags, sc1 MALL h-relay, one-asm-node h-fetch, f32 c-state in regs.
//
// Block (dir=bid>>6, kb=bid&63) owns 8 hidden units as 32 permuted gate cols:
//   tile t4 in {0,1}, lane col c in [0,16): gate g = c&3, unit jj = 2*(c>>2)+t4
//   orig Wih/Whh row = g*512 + kb*8 + jj.

typedef float  f32x4  __attribute__((ext_vector_type(4)));
typedef __bf16 bf16x8 __attribute__((ext_vector_type(8)));
typedef __bf16 bf16;

#define HB_OFF   ((size_t)0)        // 4 x [64 x 512] bf16 = 262144 B
#define FLAG_OFF ((size_t)262144)   // 512 x u32 = 2048 B
#define XF_OFF   ((size_t)264192)   // 1024 x u16 xproj group flags (new path)
                                    // (same bytes are ZROW in the legacy path)
#define WS_ZERO_BYTES ((size_t)266240)
#define XP_OFF   ((size_t)266240)                 // 128 blk*128 s*2048 f32
#define XP_BYTES ((size_t)134217728)
#define EBF_OFF  (XP_OFF + XP_BYTES)              // 8192 rows * 512 bf16
#define EBF_BYTES ((size_t)8388608)
#define WS_NEED  (EBF_OFF + EBF_BYTES)            // 142,872,576 B (unchanged)

__device__ __forceinline__ float sigmoidf_(float x) {
    return 1.0f / (1.0f + __expf(-x));
}
__device__ __forceinline__ float tanhf_(float x) {
    return 2.0f * sigmoidf_(2.0f * x) - 1.0f;
}
__device__ __forceinline__ bf16x8 cvt8(const float* p) {
    float4 a = *(const float4*)p;
    float4 b = *(const float4*)(p + 4);
    bf16x8 r;
    r[0] = (bf16)a.x; r[1] = (bf16)a.y; r[2] = (bf16)a.z; r[3] = (bf16)a.w;
    r[4] = (bf16)b.x; r[5] = (bf16)b.y; r[6] = (bf16)b.z; r[7] = (bf16)b.w;
    return r;
}
__device__ __forceinline__ bf16x8 cvt8v(uint4 u0, uint4 u1) {
    float4 a = __builtin_bit_cast(float4, u0);
    float4 b = __builtin_bit_cast(float4, u1);
    bf16x8 r;
    r[0] = (bf16)a.x; r[1] = (bf16)a.y; r[2] = (bf16)a.z; r[3] = (bf16)a.w;
    r[4] = (bf16)b.x; r[5] = (bf16)b.y; r[6] = (bf16)b.z; r[7] = (bf16)b.w;
    return r;
}
__device__ __forceinline__ void store4_sc1(float* p, f32x4 v) {
    asm volatile("global_store_dwordx4 %0, %1, off sc1"
                 :: "v"((unsigned long long)p), "v"(v) : "memory");
}
__device__ __forceinline__ void wait_xf(unsigned long long a) {
    for (;;) {
        unsigned v;
        asm volatile("global_load_ushort %0, %1, off sc1\n\t"
                     "s_waitcnt vmcnt(0)"
                     : "=&v"(v) : "v"(a) : "memory");
        if (v != 0) break;
        __builtin_amdgcn_s_sleep(2);
    }
}

__global__ __launch_bounds__(256) void init_ws_legacy(unsigned long long* __restrict__ w) {
    const size_t i = (size_t)blockIdx.x * 256 + threadIdx.x;
    if (i < WS_ZERO_BYTES / 8) w[i] = 0ull;
}

// ---- pre-pass: gather + f32->bf16 embedding rows; pad rows zeroed.
// Blocks 0..129 also zero the 266 KB scan region (hbuf + relay flags + XF).
__global__ __launch_bounds__(256) void emb_gather(
    const int* __restrict__ data, const float* __restrict__ table,
    bf16* __restrict__ ebf, unsigned long long* __restrict__ wz)
{
    const int bid = blockIdx.x, tid = threadIdx.x;
    if (bid < 130) {                                // 130*256*8 = 266240 B
        wz[(size_t)bid * 256 + tid] = 0ull;
    }
    const int wave = tid >> 6, lane = tid & 63;
    const int rr = bid * 4 + wave;                  // 0..8191 = t*64+b
    const int qv = data[rr];
    bf16x8 v;
    if (qv >= 0) {
        v = cvt8(table + (size_t)qv * 512 + lane * 8);
    } else {
#pragma unroll
        for (int i = 0; i < 8; ++i) v[i] = (bf16)0.f;
    }
    *(bf16x8*)(ebf + (size_t)rr * 512 + lane * 8) = v;
}

// ---- fused kernel: scan role (bid<128) + xproj role (bid>=128) ----
__global__ __launch_bounds__(256, 1) void fused_scan(
    const float* __restrict__ mask,
    const float* __restrict__ whh_f, const float* __restrict__ whh_b,
    const float* __restrict__ bih_f, const float* __restrict__ bhh_f,
    const float* __restrict__ bih_b, const float* __restrict__ bhh_b,
    const float* __restrict__ wih_f, const float* __restrict__ wih_b,
    const bf16* __restrict__ ebf,
    float* __restrict__ xp,
    bf16* __restrict__ hbuf,
    unsigned* __restrict__ flags,
    unsigned short* __restrict__ xf,
    float* __restrict__ out)
{
    __shared__ bf16 sM[4096 * 8];      // 64 KB; scan role uses first 32 KB

    const int tid = threadIdx.x, bid = blockIdx.x;
    const int wave = tid >> 6, lane = tid & 63;
    const int c = lane & 15, q = lane >> 4;

    if (bid >= 128) {
        // ================= xproj role =================
        // xbid = dir*512 + cc*16 + sh; computes xp for kb=2cc,2cc+1, steps
        // sh*8..sh*8+7, in the scan's exact per-lane layout (kc-ascending
        // MFMA order -> bitwise-identical numerics to round-12).
        const int xbid = bid - 128;
        const int dir = xbid >> 9, cc = (xbid >> 4) & 31, sh = xbid & 15;
        const float* wih = dir ? wih_b : wih_f;

        for (int e = tid; e < 4096; e += 256) {
            const int ec = e & 15, eq = (e >> 4) & 3, et = (e >> 6) & 3, ekc = e >> 8;
            const int kbx = 2 * cc + (et >> 1), t4x = et & 1;
            const size_t orig = (size_t)((ec & 3) * 512 + kbx * 8 + 2 * (ec >> 2) + t4x);
            *(bf16x8*)(&sM[e * 8]) = cvt8(&wih[orig * 512 + ekc * 32 + eq * 8]);
        }
        __syncthreads();

        const int hrow = 16 * wave + c;
        const f32x4 zz = {0.f, 0.f, 0.f, 0.f};
        const size_t flin = (size_t)wave * 512 + (q * 16 + c) * 8;

        for (int s0 = 0; s0 < 8; ++s0) {
            const int s = sh * 8 + s0;
            const int tt = dir ? (127 - s) : s;
            const bf16* arow = ebf + (size_t)(tt * 64 + hrow) * 512;
            uint4 af[16];
#pragma unroll
            for (int kc = 0; kc < 16; ++kc)
                af[kc] = *(const uint4*)(arow + kc * 32 + q * 8);

            f32x4 acc0 = zz, acc1 = zz, acc2 = zz, acc3 = zz;
#pragma unroll
            for (int kc = 0; kc < 16; ++kc) {
                const bf16x8 a = __builtin_bit_cast(bf16x8, af[kc]);
                acc0 = __builtin_amdgcn_mfma_f32_16x16x32_bf16(
                    a, *(const bf16x8*)(&sM[(kc * 256 +   0 + q * 16 + c) * 8]), acc0, 0, 0, 0);
                acc1 = __builtin_amdgcn_mfma_f32_16x16x32_bf16(
                    a, *(const bf16x8*)(&sM[(kc * 256 +  64 + q * 16 + c) * 8]), acc1, 0, 0, 0);
                acc2 = __builtin_amdgcn_mfma_f32_16x16x32_bf16(
                    a, *(const bf16x8*)(&sM[(kc * 256 + 128 + q * 16 + c) * 8]), acc2, 0, 0, 0);
                acc3 = __builtin_amdgcn_mfma_f32_16x16x32_bf16(
                    a, *(const bf16x8*)(&sM[(kc * 256 + 192 + q * 16 + c) * 8]), acc3, 0, 0, 0);
            }
            const size_t r0 = ((size_t)(dir * 64 + 2 * cc)     * 128 + s) * 2048 + flin;
            const size_t r1 = ((size_t)(dir * 64 + 2 * cc + 1) * 128 + s) * 2048 + flin;
            store4_sc1(&xp[r0],     acc0);      // kb=2cc,  t4=0
            store4_sc1(&xp[r0 + 4], acc1);      // kb=2cc,  t4=1
            store4_sc1(&xp[r1],     acc2);      // kb=2cc+1,t4=0
            store4_sc1(&xp[r1 + 4], acc3);      // kb=2cc+1,t4=1
        }
        __builtin_amdgcn_s_waitcnt(0x0F70);     // this wave's sc1 stores acked
        __syncthreads();                        // all 4 waves acked
        if (tid == 0) {
            const unsigned long long fa =
                (unsigned long long)&xf[(dir * 32 + cc) * 16 + sh];
            asm volatile("global_store_short %0, %1, off sc1"
                         :: "v"(fa), "v"(1u) : "memory");
        }
        return;
    }

    // ================= scan role (verbatim round-10/12 + XF gating) =========
    const int dir = bid >> 6, kb = bid & 63;
    const int g = c & 3;

    const float* whh = dir ? whh_b : whh_f;
    const float* bih = dir ? bih_b : bih_f;
    const float* bhh = dir ? bhh_b : bhh_f;

    for (int e = tid; e < 2048; e += 256) {
        const int ec = e & 15, eq = (e >> 4) & 3, et = (e >> 6) & 1, ekc = e >> 7;
        const size_t orig = (size_t)((ec & 3) * 512 + kb * 8 + 2 * (ec >> 2) + et);
        *(bf16x8*)(&sM[e * 8]) = cvt8(&whh[orig * 512 + ekc * 32 + eq * 8]);
    }
    float bias_v[2];
#pragma unroll
    for (int t4 = 0; t4 < 2; ++t4) {
        const int orig = g * 512 + kb * 8 + 2 * (c >> 2) + t4;
        bias_v[t4] = bih[orig] + bhh[orig];
    }

    float cst[2][4] = {{0.f, 0.f, 0.f, 0.f}, {0.f, 0.f, 0.f, 0.f}};
    const int hrow = 16 * wave + c;
    const int myflag = dir * 256 + wave * 64 + kb;
    const int fidx   = dir * 256 + wave * 64 + lane;
    const f32x4 zz = {0.f, 0.f, 0.f, 0.f};
    __syncthreads();                    // sM(=sW) ready; no syncs after this

    // xproj group-flag base for this block's (dir, cc=kb>>1)
    const unsigned long long xfb =
        (unsigned long long)(xf + ((size_t)(dir * 32 + (kb >> 1)) * 16));

    // prologue: wait group 0, then x-gate fragment + mask for step 0
    const float* xpb = xp + (size_t)bid * 128 * 2048
                          + (size_t)wave * 512 + (q * 16 + c) * 8;
    wait_xf(xfb);
    float4 xq0, xq1;
    {
        uint4 u0, u1;
        const unsigned long long xa = (unsigned long long)xpb;
        asm volatile("global_load_dwordx4 %0, %2, off sc1\n\t"
                     "global_load_dwordx4 %1, %2, off offset:16 sc1\n\t"
                     "s_waitcnt vmcnt(0)"
                     : "=&v"(u0), "=&v"(u1) : "v"(xa) : "memory");
        xq0 = __builtin_bit_cast(float4, u0);
        xq1 = __builtin_bit_cast(float4, u1);
    }
    float4 mv;
    {
        const int tt0 = dir ? 127 : 0;
        mv = *(const float4*)(&mask[tt0 * 64 + 16 * wave + 4 * q]);
    }

    for (int s = 0; s < 128; ++s) {
        const int tt = dir ? (127 - s) : s;

        // ---- wait: the 64 wave-matched producer waves completed step s-1 ----
        const unsigned tgt = (unsigned)s;
        unsigned fa = __hip_atomic_load(flags + fidx, __ATOMIC_RELAXED, __HIP_MEMORY_SCOPE_AGENT);
        unsigned fb = __hip_atomic_load(flags + fidx, __ATOMIC_RELAXED, __HIP_MEMORY_SCOPE_AGENT);
        for (;;) {
            if (__all(fa >= tgt)) break;
            fa = fb;
            fb = __hip_atomic_load(flags + fidx, __ATOMIC_RELAXED, __HIP_MEMORY_SCOPE_AGENT);
        }
        __asm__ volatile("" ::: "memory");   // keep h-loads below the poll

        const bf16* hb = hbuf + (size_t)(dir * 2 + (s & 1)) * (64 * 512);
        bf16*       hw = hbuf + (size_t)(dir * 2 + ((s + 1) & 1)) * (64 * 512);

        // ---- h A-fragments: ONE asm node = 16 sc1 dwordx4 + vmcnt(0) ----
        const unsigned long long ha =
            (unsigned long long)hb + (unsigned)(hrow * 1024 + q * 16);
        uint4 af[16];
        asm volatile(
            "global_load_dwordx4 %0,  %16, off sc1\n\t"
            "global_load_dwordx4 %1,  %16, off offset:64   sc1\n\t"
            "global_load_dwordx4 %2,  %16, off offset:128  sc1\n\t"
            "global_load_dwordx4 %3,  %16, off offset:192  sc1\n\t"
            "global_load_dwordx4 %4,  %16, off offset:256  sc1\n\t"
            "global_load_dwordx4 %5,  %16, off offset:320  sc1\n\t"
            "global_load_dwordx4 %6,  %16, off offset:384  sc1\n\t"
            "global_load_dwordx4 %7,  %16, off offset:448  sc1\n\t"
            "global_load_dwordx4 %8,  %16, off offset:512  sc1\n\t"
            "global_load_dwordx4 %9,  %16, off offset:576  sc1\n\t"
            "global_load_dwordx4 %10, %16, off offset:640  sc1\n\t"
            "global_load_dwordx4 %11, %16, off offset:704  sc1\n\t"
            "global_load_dwordx4 %12, %16, off offset:768  sc1\n\t"
            "global_load_dwordx4 %13, %16, off offset:832  sc1\n\t"
            "global_load_dwordx4 %14, %16, off offset:896  sc1\n\t"
            "global_load_dwordx4 %15, %16, off offset:960  sc1\n\t"
            "s_waitcnt vmcnt(0)"
            : "=&v"(af[0]),  "=&v"(af[1]),  "=&v"(af[2]),  "=&v"(af[3]),
              "=&v"(af[4]),  "=&v"(af[5]),  "=&v"(af[6]),  "=&v"(af[7]),
              "=&v"(af[8]),  "=&v"(af[9]),  "=&v"(af[10]), "=&v"(af[11]),
              "=&v"(af[12]), "=&v"(af[13]), "=&v"(af[14]), "=&v"(af[15])
            : "v"(ha)
            : "memory");

        f32x4 acc0 = zz, acc1 = zz;
#pragma unroll
        for (int kc = 0; kc < 16; ++kc) {
            const bf16x8 a  = __builtin_bit_cast(bf16x8, af[kc]);
            const bf16x8 b0 = *(const bf16x8*)(&sM[(kc * 128 + q * 16 + c) * 8]);
            const bf16x8 b1 = *(const bf16x8*)(&sM[(kc * 128 + 64 + q * 16 + c) * 8]);
            acc0 = __builtin_amdgcn_mfma_f32_16x16x32_bf16(a, b0, acc0, 0, 0, 0);
            acc1 = __builtin_amdgcn_mfma_f32_16x16x32_bf16(a, b1, acc1, 0, 0, 0);
        }

        // ---- epilogue: C/D layout col=lane&15, row=q*4+r ----
        unsigned* hw32 = (unsigned*)hw;
        float hreg[4][2];
#pragma unroll
        for (int r = 0; r < 4; ++r) {
            const int b_ = 16 * wave + 4 * q + r;
            const float m = (&mv.x)[r];
            float hv01[2];
#pragma unroll
            for (int t4 = 0; t4 < 2; ++t4) {
                float v = (t4 ? acc1[r] : acc0[r])
                        + (t4 ? (&xq1.x)[r] : (&xq0.x)[r]) + bias_v[t4];
                const float v1 = __shfl_xor(v, 1);
                const float v2 = __shfl_xor(v, 2);
                const float v3 = __shfl_xor(v, 3);
                const float gi = (g == 0) ? v  : (g == 1) ? v1 : (g == 2) ? v2 : v3;
                const float gf = (g == 0) ? v1 : (g == 1) ? v  : (g == 2) ? v3 : v2;
                const float gG = (g == 0) ? v2 : (g == 1) ? v3 : (g == 2) ? v  : v1;
                const float go = (g == 0) ? v3 : (g == 1) ? v2 : (g == 2) ? v1 : v;
                const float cn = sigmoidf_(gf) * cst[t4][r] + sigmoidf_(gi) * tanhf_(gG);
                float hv       = sigmoidf_(go) * tanhf_(cn);
                cst[t4][r] = cn * m;
                hv *= m;
                hv01[t4] = hv;
            }
            hreg[r][0] = hv01[0]; hreg[r][1] = hv01[1];
            if (g == 0) {                   // packed 2xbf16 -> one u32 sc1 store
                const unsigned u =
                    (unsigned)__builtin_bit_cast(unsigned short, (bf16)hv01[0]) |
                    ((unsigned)__builtin_bit_cast(unsigned short, (bf16)hv01[1]) << 16);
                __hip_atomic_store(hw32 + b_ * 256 + kb * 4 + (c >> 2), u,
                                   __ATOMIC_RELAXED, __HIP_MEMORY_SCOPE_AGENT);
            }
        }

        // release: all h sc1-stores acked at MALL before flag store
        __asm__ volatile("" ::: "memory");
        __builtin_amdgcn_s_waitcnt(0x0F70);  // vmcnt(0)
        if (lane == 0)
            __hip_atomic_store(flags + myflag, (unsigned)(s + 1),
                               __ATOMIC_RELAXED, __HIP_MEMORY_SCOPE_AGENT);

        // ---- step tail (hidden behind other blocks' consumption) ----
        if (g == 0) {
            const int j2 = dir * 512 + kb * 8 + 2 * (c >> 2);
#pragma unroll
            for (int r = 0; r < 4; ++r) {
                const int b_ = 16 * wave + 4 * q + r;
                float2 o2; o2.x = hreg[r][0]; o2.y = hreg[r][1];
                *(float2*)(&out[(size_t)(tt * 64 + b_) * 1024 + j2]) = o2;
            }
        }
        if (s < 127) {
            if (((s + 1) & 7) == 0)                 // new 8-step group
                wait_xf(xfb + (unsigned)(((s + 1) >> 3) * 2));
            uint4 u0, u1;
            const unsigned long long xa =
                (unsigned long long)(xpb + (size_t)(s + 1) * 2048);
            asm volatile("global_load_dwordx4 %0, %2, off sc1\n\t"
                         "global_load_dwordx4 %1, %2, off offset:16 sc1\n\t"
                         "s_waitcnt vmcnt(0)"
                         : "=&v"(u0), "=&v"(u1) : "v"(xa) : "memory");
            xq0 = __builtin_bit_cast(float4, u0);
            xq1 = __builtin_bit_cast(float4, u1);
            const int tt_n = dir ? (126 - s) : (s + 1);
            mv  = *(const float4*)(&mask[tt_n * 64 + 16 * wave + 4 * q]);
        }
    }
}

// ================= verbatim round-9 fallback (ws too small) =================
__global__ __launch_bounds__(256, 1) void lstm_scan_legacy(
    const int*   __restrict__ data,
    const float* __restrict__ mask,
    const float* __restrict__ table,
    const float* __restrict__ wih_f, const float* __restrict__ whh_f,
    const float* __restrict__ bih_f, const float* __restrict__ bhh_f,
    const float* __restrict__ wih_b, const float* __restrict__ whh_b,
    const float* __restrict__ bih_b, const float* __restrict__ bhh_b,
    bf16* __restrict__ hbuf,
    unsigned* __restrict__ flags,
    const float* __restrict__ zrow,
    float* __restrict__ out)
{
    __shared__ bf16 sW[2048 * 8];
    __shared__ bf16 sV[2048 * 8];

    const int tid = threadIdx.x, bid = blockIdx.x;
    const int dir = bid >> 6, kb = bid & 63;
    const int wave = tid >> 6, lane = tid & 63;
    const int c = lane & 15, q = lane >> 4, g = c & 3;

    const float* wih = dir ? wih_b : wih_f;
    const float* whh = dir ? whh_b : whh_f;
    const float* bih = dir ? bih_b : bih_f;
    const float* bhh = dir ? bhh_b : bhh_f;

    for (int e = tid; e < 2048; e += 256) {
        const int ec = e & 15, eq = (e >> 4) & 3, et = (e >> 6) & 1, ekc = e >> 7;
        const size_t orig = (size_t)((ec & 3) * 512 + kb * 8 + 2 * (ec >> 2) + et);
        const size_t off = orig * 512 + ekc * 32 + eq * 8;
        *(bf16x8*)(&sW[e * 8]) = cvt8(&whh[off]);
        *(bf16x8*)(&sV[e * 8]) = cvt8(&wih[off]);
    }
    float bias_v[2];
#pragma unroll
    for (int t4 = 0; t4 < 2; ++t4) {
        const int orig = g * 512 + kb * 8 + 2 * (c >> 2) + t4;
        bias_v[t4] = bih[orig] + bhh[orig];
    }

    float cst[2][4] = {{0.f, 0.f, 0.f, 0.f}, {0.f, 0.f, 0.f, 0.f}};
    const int hrow = 16 * wave + c;
    const int myflag = dir * 256 + kb * 4 + wave;
    const int fbase = dir * 256;
    const f32x4 zz = {0.f, 0.f, 0.f, 0.f};
    __syncthreads();

    uint4 xe[32];
    float4 mv;
    int qv_n;
    {
        const int tt0 = dir ? 127 : 0;
        const int qv0 = data[tt0 * 64 + hrow];
        mv = *(const float4*)(&mask[tt0 * 64 + 16 * wave + 4 * q]);
        const float* erow = (qv0 >= 0) ? (table + (size_t)qv0 * 512) : zrow;
#pragma unroll
        for (int kc = 0; kc < 16; ++kc) {
            xe[2 * kc]     = *(const uint4*)(erow + kc * 32 + q * 8);
            xe[2 * kc + 1] = *(const uint4*)(erow + kc * 32 + q * 8 + 4);
        }
        const int tt1 = dir ? 126 : 1;
        qv_n = data[tt1 * 64 + hrow];
    }

    for (int s = 0; s < 128; ++s) {
        const int tt = dir ? (127 - s) : s;

        f32x4 accx0 = zz, accx1 = zz;
#pragma unroll
        for (int kc = 0; kc < 16; ++kc) {
            const bf16x8 e  = cvt8v(xe[2 * kc], xe[2 * kc + 1]);
            const bf16x8 b0 = *(const bf16x8*)(&sV[(kc * 128 + q * 16 + c) * 8]);
            const bf16x8 b1 = *(const bf16x8*)(&sV[(kc * 128 + 64 + q * 16 + c) * 8]);
            accx0 = __builtin_amdgcn_mfma_f32_16x16x32_bf16(e, b0, accx0, 0, 0, 0);
            accx1 = __builtin_amdgcn_mfma_f32_16x16x32_bf16(e, b1, accx1, 0, 0, 0);
        }

        const unsigned tgt = (unsigned)s;
        for (;;) {
            const unsigned a0 = __hip_atomic_load(flags + fbase + lane,       __ATOMIC_RELAXED, __HIP_MEMORY_SCOPE_AGENT);
            const unsigned a1 = __hip_atomic_load(flags + fbase + 64  + lane, __ATOMIC_RELAXED, __HIP_MEMORY_SCOPE_AGENT);
            const unsigned a2 = __hip_atomic_load(flags + fbase + 128 + lane, __ATOMIC_RELAXED, __HIP_MEMORY_SCOPE_AGENT);
            const unsigned a3 = __hip_atomic_load(flags + fbase + 192 + lane, __ATOMIC_RELAXED, __HIP_MEMORY_SCOPE_AGENT);
            if (__all(a0 >= tgt && a1 >= tgt && a2 >= tgt && a3 >= tgt)) break;
            __builtin_amdgcn_s_sleep(1);
        }
        __asm__ volatile("" ::: "memory");

        const bf16* hb = hbuf + (size_t)(dir * 2 + (s & 1)) * (64 * 512);
        bf16*       hw = hbuf + (size_t)(dir * 2 + ((s + 1) & 1)) * (64 * 512);

        const unsigned long long ha =
            (unsigned long long)hb + (unsigned)(hrow * 1024 + q * 16);
        uint4 af[16];
        asm volatile(
            "global_load_dwordx4 %0,  %16, off sc1\n\t"
            "global_load_dwordx4 %1,  %16, off offset:64   sc1\n\t"
            "global_load_dwordx4 %2,  %16, off offset:128  sc1\n\t"
            "global_load_dwordx4 %3,  %16, off offset:192  sc1\n\t"
            "global_load_dwordx4 %4,  %16, off offset:256  sc1\n\t"
            "global_load_dwordx4 %5,  %16, off offset:320  sc1\n\t"
            "global_load_dwordx4 %6,  %16, off offset:384  sc1\n\t"
            "global_load_dwordx4 %7,  %16, off offset:448  sc1\n\t"
            "global_load_dwordx4 %8,  %16, off offset:512  sc1\n\t"
            "global_load_dwordx4 %9,  %16, off offset:576  sc1\n\t"
            "global_load_dwordx4 %10, %16, off offset:640  sc1\n\t"
            "global_load_dwordx4 %11, %16, off offset:704  sc1\n\t"
            "global_load_dwordx4 %12, %16, off offset:768  sc1\n\t"
            "global_load_dwordx4 %13, %16, off offset:832  sc1\n\t"
            "global_load_dwordx4 %14, %16, off offset:896  sc1\n\t"
            "global_load_dwordx4 %15, %16, off offset:960  sc1\n\t"
            "s_waitcnt vmcnt(0)"
            : "=&v"(af[0]),  "=&v"(af[1]),  "=&v"(af[2]),  "=&v"(af[3]),
              "=&v"(af[4]),  "=&v"(af[5]),  "=&v"(af[6]),  "=&v"(af[7]),
              "=&v"(af[8]),  "=&v"(af[9]),  "=&v"(af[10]), "=&v"(af[11]),
              "=&v"(af[12]), "=&v"(af[13]), "=&v"(af[14]), "=&v"(af[15])
            : "v"(ha)
            : "memory");

        f32x4 acc0 = zz, acc1 = zz;
#pragma unroll
        for (int kc = 0; kc < 16; ++kc) {
            const bf16x8 a  = __builtin_bit_cast(bf16x8, af[kc]);
            const bf16x8 b0 = *(const bf16x8*)(&sW[(kc * 128 + q * 16 + c) * 8]);
            const bf16x8 b1 = *(const bf16x8*)(&sW[(kc * 128 + 64 + q * 16 + c) * 8]);
            acc0 = __builtin_amdgcn_mfma_f32_16x16x32_bf16(a, b0, acc0, 0, 0, 0);
            acc1 = __builtin_amdgcn_mfma_f32_16x16x32_bf16(a, b1, acc1, 0, 0, 0);
        }

        unsigned* hw32 = (unsigned*)hw;
        float hreg[4][2];
#pragma unroll
        for (int r = 0; r < 4; ++r) {
            const int b_ = 16 * wave + 4 * q + r;
            const float m = (&mv.x)[r];
            float hv01[2];
#pragma unroll
            for (int t4 = 0; t4 < 2; ++t4) {
                float v = (t4 ? acc1[r] : acc0[r]) + (t4 ? accx1[r] : accx0[r]) + bias_v[t4];
                const float v1 = __shfl_xor(v, 1);
                const float v2 = __shfl_xor(v, 2);
                const float v3 = __shfl_xor(v, 3);
                const float gi = (g == 0) ? v  : (g == 1) ? v1 : (g == 2) ? v2 : v3;
                const float gf = (g == 0) ? v1 : (g == 1) ? v  : (g == 2) ? v3 : v2;
                const float gG = (g == 0) ? v2 : (g == 1) ? v3 : (g == 2) ? v  : v1;
                const float go = (g == 0) ? v3 : (g == 1) ? v2 : (g == 2) ? v1 : v;
                const float cn = sigmoidf_(gf) * cst[t4][r] + sigmoidf_(gi) * tanhf_(gG);
                float hv       = sigmoidf_(go) * tanhf_(cn);
                cst[t4][r] = cn * m;
                hv *= m;
                hv01[t4] = hv;
            }
            hreg[r][0] = hv01[0]; hreg[r][1] = hv01[1];
            if (g == 0) {
                const unsigned u =
                    (unsigned)__builtin_bit_cast(unsigned short, (bf16)hv01[0]) |
                    ((unsigned)__builtin_bit_cast(unsigned short, (bf16)hv01[1]) << 16);
                __hip_atomic_store(hw32 + b_ * 256 + kb * 4 + (c >> 2), u,
                                   __ATOMIC_RELAXED, __HIP_MEMORY_SCOPE_AGENT);
            }
        }

        __asm__ volatile("" ::: "memory");
        __builtin_amdgcn_s_waitcnt(0x0F70);
        if (lane == 0)
            __hip_atomic_store(flags + myflag, (unsigned)(s + 1),
                               __ATOMIC_RELAXED, __HIP_MEMORY_SCOPE_AGENT);

        if (g == 0) {
            const int j2 = dir * 512 + kb * 8 + 2 * (c >> 2);
#pragma unroll
            for (int r = 0; r < 4; ++r) {
                const int b_ = 16 * wave + 4 * q + r;
                float2 o2; o2.x = hreg[r][0]; o2.y = hreg[r][1];
                *(float2*)(&out[(size_t)(tt * 64 + b_) * 1024 + j2]) = o2;
            }
        }
        if (s < 127) {
            const int tt_n = dir ? (126 - s) : (s + 1);
            const float* erow = (qv_n >= 0) ? (table + (size_t)qv_n * 512) : zrow;
#pragma unroll
            for (int kc = 0; kc < 16; ++kc) {
                xe[2 * kc]     = *(const uint4*)(erow + kc * 32 + q * 8);
                xe[2 * kc + 1] = *(const uint4*)(erow + kc * 32 + q * 8 + 4);
            }
            mv = *(const float4*)(&mask[tt_n * 64 + 16 * wave + 4 * q]);
            if (s < 126) {
                const int tt_n2 = dir ? (125 - s) : (s + 2);
                qv_n = data[tt_n2 * 64 + hrow];
            }
        }
    }
}

extern "C" void kernel_launch(void* const* d_in, const int* in_sizes, int n_in,
                              void* d_out, int out_size, void* d_ws, size_t ws_size,
                              hipStream_t stream) {
    const int*   data  = (const int*)d_in[0];
    const float* mask  = (const float*)d_in[1];
    const float* table = (const float*)d_in[2];
    const float* wih_f = (const float*)d_in[3];
    const float* whh_f = (const float*)d_in[4];
    const float* bih_f = (const float*)d_in[5];
    const float* bhh_f = (const float*)d_in[6];
    const float* wih_b = (const float*)d_in[7];
    const float* whh_b = (const float*)d_in[8];
    const float* bih_b = (const float*)d_in[9];
    const float* bhh_b = (const float*)d_in[10];
    float* outp = (float*)d_out;

    char* ws = (char*)d_ws;
    bf16*     hbuf  = (bf16*)(ws + HB_OFF);
    unsigned* flagp = (unsigned*)(ws + FLAG_OFF);

    if (ws_size >= WS_NEED) {
        bf16*  ebf = (bf16*)(ws + EBF_OFF);
        float* xp  = (float*)(ws + XP_OFF);
        unsigned short* xf = (unsigned short*)(ws + XF_OFF);
        emb_gather<<<2048, 256, 0, stream>>>(data, table, ebf,
                                             (unsigned long long*)ws);
        fused_scan<<<1152, 256, 0, stream>>>(mask, whh_f, whh_b,
                                             bih_f, bhh_f, bih_b, bhh_b,
                                             wih_f, wih_b, ebf, xp,
                                             hbuf, flagp, xf, outp);
    } else {
        const float* zrow = (const float*)(ws + XF_OFF);   // legacy zrow bytes
        init_ws_legacy<<<(int)((WS_ZERO_BYTES / 8 + 255) / 256), 256, 0, stream>>>(
            (unsigned long long*)ws);
        lstm_scan_legacy<<<128, 256, 0, stream>>>(data, mask, table,
                                                  wih_f, whh_f, bih_f, bhh_f,
                                                  wih_b, whh_b, bih_b, bhh_b,
                                                  hbuf, flagp, zrow, outp);
    }
}